// Round 8
// baseline (221.191 us; speedup 1.0000x reference)
//
#include <hip/hip_runtime.h>
#include <stdint.h>

#define SS   8192
#define DIMD 1024
#define NCH  128
#define CC   16
#define EPSF 1e-8f

typedef __bf16 bh;
typedef bh    bhx4 __attribute__((ext_vector_type(4)));
typedef bh    bhx8 __attribute__((ext_vector_type(8)));
typedef float fx4  __attribute__((ext_vector_type(4)));
typedef unsigned int u32x2 __attribute__((ext_vector_type(2)));

#define GLOAD_LDS16(g, l) __builtin_amdgcn_global_load_lds(                    \
    (const __attribute__((address_space(1))) uint32_t*)(g),                    \
    (__attribute__((address_space(3))) uint32_t*)(l), 16, 0, 0)

#define LDSA(p) ((uint32_t)(uintptr_t)(const __attribute__((address_space(3))) char*)(const char*)(p))

#define SB() __builtin_amdgcn_sched_barrier(0)
#define PRE_BAR()  do { SB(); __builtin_amdgcn_s_barrier(); SB();              \
                        __builtin_amdgcn_s_setprio(1); } while (0)
#define POST_BAR() do { __builtin_amdgcn_s_setprio(0); SB();                   \
                        __builtin_amdgcn_s_barrier(); SB(); } while (0)

// ---------------- f32 -> bf16 convert (Wv only) -----------------------------
__global__ __launch_bounds__(256) void cvt_k(const float* __restrict__ src,
                                             bh* __restrict__ dst, int n8) {
    int i = blockIdx.x * 256 + threadIdx.x;
    if (i >= n8) return;
    const float4 a = reinterpret_cast<const float4*>(src)[i * 2];
    const float4 b = reinterpret_cast<const float4*>(src)[i * 2 + 1];
    bhx8 o;
    o[0] = (bh)a.x; o[1] = (bh)a.y; o[2] = (bh)a.z; o[3] = (bh)a.w;
    o[4] = (bh)b.x; o[5] = (bh)b.y; o[6] = (bh)b.z; o[7] = (bh)b.w;
    reinterpret_cast<bhx8*>(dst)[i] = o;
}

#define CVT8(v, f0, f1)                                                        \
    { v[0]=(bh)(f0).x; v[1]=(bh)(f0).y; v[2]=(bh)(f0).z; v[3]=(bh)(f0).w;      \
      v[4]=(bh)(f1).x; v[5]=(bh)(f1).y; v[6]=(bh)(f1).z; v[7]=(bh)(f1).w; }

// ---------------- fused cvt+GEMM+ka: C = bf16(A_f32) @ Bw^T -----------------
// A staged AS F32 via global_load_lds (no staging registers -> no spills,
// the R2/R7 failure mechanism).  BK=32, 2 phases/tile, 16 MFMA each.
// LDS 128 KiB: A f32 triple-buffer 3x[256][128B] at 0/32K/64K (t+2 staging
// never aliases t / t-1 readers); B bf16 dbuf 2x[256][64B] at 96K/112K.
// A swizzle (derived for 128B rows, banks alias by slot only):
//   phys16Bslot = logical ^ (row&7)  (3-bit XOR; a0/a1 partner = addr^16)
// applied on pre-swizzled global source AND on fragment read (involution).
// vmcnt ledger: 6 loads staged/tile (A4 in P1, B2 in P2); end-of-tile
// vmcnt(6) => tile t+1 landed, t+2 in flight; t=30 -> vmcnt(0); t=31 none.
template <typename VT>
__global__ __launch_bounds__(512, 2) void gemm256f3(const float* __restrict__ A,
                                                    const bh* __restrict__ Bw,
                                                    VT* __restrict__ C,
                                                    const int* __restrict__ tsp,
                                                    const float* __restrict__ gammap,
                                                    float* __restrict__ Aws,
                                                    float* __restrict__ plastWs) {
    __shared__ __align__(16) char ldsraw[131072];
    const int lb = blockIdx.x;
    const int logical = (lb & 7) * 64 + (lb >> 3);   // XCD-chunked, bijective (512 wg)
    const int mt = logical >> 2;                     // 128 m-tiles
    const int nt = logical & 3;                      // 4 n-tiles
    const int tid = threadIdx.x, lane = tid & 63, w = tid >> 6;
    const int wm = w >> 2, wn = w & 3;

    fx4 acc[8][4];
#pragma unroll
    for (int i = 0; i < 8; ++i)
#pragma unroll
        for (int j = 0; j < 4; ++j)
#pragma unroll
            for (int r = 0; r < 4; ++r) acc[i][j][r] = 0.f;

    // A staging source: dest row = i*64 + (tid>>3), phys slot = tid&7;
    // logical slot = phys ^ (row&7) = (tid&7)^((tid>>3)&7); 4 f32 per slot.
    const float* gAf = A + (size_t)(mt * 256 + (tid >> 3)) * DIMD
                       + ((tid & 7) ^ ((tid >> 3) & 7)) * 4;
    // B staging source: dest row = i*128 + (tid>>2), slot = tid&3;
    // logical k-group = slot ^ ((row>>1)&3) = (tid&3)^((tid>>3)&3); 8 bf16 each.
    const bh* gB0 = Bw + (size_t)(nt * 256 + (tid >> 2)) * DIMD
                    + ((tid & 3) ^ ((tid >> 3) & 3)) * 8;

#define STAGE_A(KT, AU)                                                        \
    { char* lp_ = ldsraw + (AU) * 32768 + tid * 16;                            \
      const float* gp_ = gAf + (size_t)(KT) * 32;                              \
      GLOAD_LDS16(gp_,          lp_);                                          \
      GLOAD_LDS16(gp_ + 65536,  lp_ + 8192);                                   \
      GLOAD_LDS16(gp_ + 131072, lp_ + 16384);                                  \
      GLOAD_LDS16(gp_ + 196608, lp_ + 24576); }

#define STAGE_B(KT, BB)                                                        \
    { char* lp_ = ldsraw + 98304 + (BB) * 16384 + tid * 16;                    \
      const bh* gp_ = gB0 + (size_t)(KT) * 32;                                 \
      GLOAD_LDS16(gp_,          lp_);                                          \
      GLOAD_LDS16(gp_ + 131072, lp_ + 8192); }

    // A frag read: row = wm*128 + mi*16 + (lane&15); g = lane>>4 (8 f32);
    // byte = row*128 + ((2g ^ (row&7))<<4); partner = addr^16.
    const int offA2 = (wm * 128 + (lane & 15)) * 128
                      + ((((lane >> 4) << 1) ^ (lane & 7)) << 4);
    // B frag read: row = wn*64 + ni*16 + (lane&15); 64B rows;
    // slot = (lane>>4) ^ ((row>>1)&3)
    const int offB = (wn * 64 + (lane & 15)) * 64
                     + (((lane >> 4) ^ (((lane & 15) >> 1) & 3)) << 4);

    // ---- prologue: tiles 0,1 ----
    STAGE_A(0, 0); STAGE_B(0, 0);
    STAGE_A(1, 1); STAGE_B(1, 1);
    asm volatile("s_waitcnt vmcnt(6)" ::: "memory");   // A0+B0 landed
    SB(); __builtin_amdgcn_s_barrier(); SB();

    int abuf = 0;
#pragma unroll 2
    for (int t = 0; t < 32; ++t) {
        const int au = abuf;
        const int au2 = (au >= 1) ? au - 1 : 2;        // (au+2)%3
        const int bb = t & 1;
        const char* pA = ldsraw + au * 32768;
        const char* pB = ldsraw + 98304 + bb * 16384;
        bhx8 fa[4], fb[4];

        // ---- P1: mq0 frags + B frags; stage A(t+2) ----
#pragma unroll
        for (int mi = 0; mi < 4; ++mi) {
            const char* a0 = pA + offA2 + mi * 2048;
            const float4 q0 = *reinterpret_cast<const float4*>(a0);
            const float4 q1 = *reinterpret_cast<const float4*>(
                (const char*)((uintptr_t)a0 ^ 16));
            CVT8(fa[mi], q0, q1);
        }
#pragma unroll
        for (int ni = 0; ni < 4; ++ni)
            fb[ni] = *reinterpret_cast<const bhx8*>(pB + offB + ni * 1024);
        if (t <= 29) STAGE_A(t + 2, au2);
        PRE_BAR();
#pragma unroll
        for (int i = 0; i < 4; ++i)
#pragma unroll
            for (int j = 0; j < 4; ++j)
                acc[i][j] = __builtin_amdgcn_mfma_f32_16x16x32_bf16(fa[i], fb[j], acc[i][j], 0, 0, 0);
        POST_BAR();

        // ---- P2: mq1 frags (fb reused); stage B(t+2) ----
#pragma unroll
        for (int mi = 0; mi < 4; ++mi) {
            const char* a0 = pA + offA2 + (4 + mi) * 2048;
            const float4 q0 = *reinterpret_cast<const float4*>(a0);
            const float4 q1 = *reinterpret_cast<const float4*>(
                (const char*)((uintptr_t)a0 ^ 16));
            CVT8(fa[mi], q0, q1);
        }
        if (t <= 29) STAGE_B(t + 2, bb);               // (t+2)&1 == bb
        PRE_BAR();
#pragma unroll
        for (int i = 0; i < 4; ++i)
#pragma unroll
            for (int j = 0; j < 4; ++j)
                acc[4 + i][j] = __builtin_amdgcn_mfma_f32_16x16x32_bf16(fa[i], fb[j], acc[4 + i][j], 0, 0, 0);
        __builtin_amdgcn_s_setprio(0);
        if (t < 30)       { asm volatile("s_waitcnt vmcnt(6)" ::: "memory"); }
        else if (t == 30) { asm volatile("s_waitcnt vmcnt(0)" ::: "memory"); }
        SB(); __builtin_amdgcn_s_barrier(); SB();
        abuf = (abuf == 2) ? 0 : abuf + 1;
    }
#undef STAGE_A
#undef STAGE_B

    // ---- C-store: col = lane&15, row = (lane>>4)*4 + r (m89-verified) ----
    const int r0 = (lane >> 4) * 4;
    const int c0 = lane & 15;
#pragma unroll
    for (int mi = 0; mi < 8; ++mi) {
#pragma unroll
        for (int ni = 0; ni < 4; ++ni) {
            const size_t m = (size_t)(mt * 256 + wm * 128 + mi * 16 + r0);
            const int    n = nt * 256 + wn * 64 + ni * 16 + c0;
#pragma unroll
            for (int r = 0; r < 4; ++r) {
                if constexpr (sizeof(VT) == 2)
                    C[(m + r) * DIMD + n] = (bh)acc[mi][ni][r];
                else
                    C[(m + r) * DIMD + n] = acc[mi][ni][r];
            }
        }
    }

    // ================= fused ka epilogue (R5 form) =================
    float* wlds = (float*)ldsraw + w * 256;
    const int b_ = mt >> 5;
    const int j0 = (mt & 31) * 4;
    const int c_ = nt * 4 + wn;
    const int h_ = c_ & 7;
    const int jg0 = j0 + wm * 2;
    float iv = 1.f; double invb = 1.0;
    for (int i = 0; i < h_; i++) { iv *= 10.f; invb *= 0.1; }
    const float sf = (float)(6.283185307179586 * invb);
    const float gm = 1.f / (1.f + expf(-gammap[h_]));
    const float lg = logf(fmaxf(gm, 1e-6f));

#pragma unroll
    for (int jl = 0; jl < 2; ++jl) {
        const int jg = jg0 + jl;
        const int sl = jg * 64 + lane;                 // batch-local index
        const int its = tsp[b_ * SS + sl];
        const int itp = (sl > 0) ? tsp[b_ * SS + sl - 1] : its;
        int dstep = its - itp; if (dstep < 0) dstep = 0;
        const float dec = expf(lg * ((float)dstep * sf));
        float p = fmaxf(dec, EPSF);
#pragma unroll
        for (int off = 1; off < 64; off <<= 1) {
            float o = __shfl_up(p, off, 64);
            if (lane >= off) p *= o;
        }
        const float plast = __shfl(p, 63, 64);
        const float swv = plast / fmaxf(p, EPSF);
        const float tk = fmodf((float)its, iv) * sf;
        wlds[jl * 128 + lane]      = cosf(tk) * swv;
        wlds[jl * 128 + 64 + lane] = sinf(tk) * swv;
        if (lane == 0) plastWs[(size_t)(b_ * CC + c_) * NCH + jg] = plast;
    }
    asm volatile("s_waitcnt lgkmcnt(0)" ::: "memory");

#pragma unroll
    for (int jl = 0; jl < 2; ++jl) {
        const int jg = jg0 + jl;
        float* ab = Aws + ((size_t)(b_ * CC + c_) * NCH + jg) * 128;
        fx4 w0q[4], w1q[4];
        const int gb = ((lane >> 4) << 2);
#pragma unroll
        for (int q = 0; q < 4; ++q) {
            w0q[q] = *reinterpret_cast<const fx4*>(&wlds[jl * 128 + q * 16 + gb]);
            w1q[q] = *reinterpret_cast<const fx4*>(&wlds[jl * 128 + 64 + q * 16 + gb]);
        }
#pragma unroll
        for (int ni = 0; ni < 4; ++ni) {
            float pa0 = 0.f, pa1 = 0.f;
#pragma unroll
            for (int q = 0; q < 4; ++q)
#pragma unroll
                for (int r = 0; r < 4; ++r) {
                    const float av = acc[jl * 4 + q][ni][r];
                    pa0 += w0q[q][r] * av;
                    pa1 += w1q[q][r] * av;
                }
            pa0 += __shfl_xor(pa0, 16, 64); pa0 += __shfl_xor(pa0, 32, 64);
            pa1 += __shfl_xor(pa1, 16, 64); pa1 += __shfl_xor(pa1, 32, 64);
            const int e = ni * 16 + (lane & 15);
            const int grp = lane >> 4;
            if (grp == 0)      ab[e] = pa0;
            else if (grp == 1) ab[64 + e] = pa1;
        }
    }
}

// ---------------- legacy f32 GEMM (tier-3 fallback) -------------------------
__global__ __launch_bounds__(256) void gemm_k(const float* __restrict__ Ain,
                                              const float* __restrict__ Win,
                                              float* __restrict__ Cout) {
    __shared__ __align__(16) char ldsraw[20480];
    char* ldsA = ldsraw;
    char* ldsB = ldsraw + 10240;
    const int tid = threadIdx.x;
    const int lane = tid & 63;
    const int w = tid >> 6;
    const int wm = w >> 1, wn = w & 1;
    const int bid = blockIdx.x;
    const int mt = bid >> 3;
    const int nt = bid & 7;
    const size_t Abase = (size_t)mt * 128 * 1024;
    const size_t Bbase = (size_t)nt * 128 * 1024;
    fx4 acc[4][4];
#pragma unroll
    for (int i = 0; i < 4; i++)
#pragma unroll
        for (int j2 = 0; j2 < 4; j2++)
#pragma unroll
            for (int r = 0; r < 4; r++) acc[i][j2][r] = 0.f;
    const int srow0 = tid >> 3;
    const int sc16 = tid & 7;
    for (int kt = 0; kt < 32; ++kt) {
        const int k0 = kt * 32;
#pragma unroll
        for (int jj = 0; jj < 4; jj++) {
            int row = srow0 + jj * 32;
            const float4 va = *reinterpret_cast<const float4*>(Ain + Abase + (size_t)row * 1024 + k0 + sc16 * 4);
            const float4 vb = *reinterpret_cast<const float4*>(Win + Bbase + (size_t)row * 1024 + k0 + sc16 * 4);
            bhx4 ba, bb2;
            ba[0] = (bh)va.x; ba[1] = (bh)va.y; ba[2] = (bh)va.z; ba[3] = (bh)va.w;
            bb2[0] = (bh)vb.x; bb2[1] = (bh)vb.y; bb2[2] = (bh)vb.z; bb2[3] = (bh)vb.w;
            *reinterpret_cast<bhx4*>(ldsA + row * 80 + sc16 * 8) = ba;
            *reinterpret_cast<bhx4*>(ldsB + row * 80 + sc16 * 8) = bb2;
        }
        __syncthreads();
        bhx8 fa[4], fb[4];
        const int kb = (lane >> 4) * 16;
        const int rA = wm * 64 + (lane & 15);
        const int rB = wn * 64 + (lane & 15);
#pragma unroll
        for (int mi = 0; mi < 4; mi++) fa[mi] = *reinterpret_cast<const bhx8*>(ldsA + (rA + mi * 16) * 80 + kb);
#pragma unroll
        for (int ni = 0; ni < 4; ni++) fb[ni] = *reinterpret_cast<const bhx8*>(ldsB + (rB + ni * 16) * 80 + kb);
#pragma unroll
        for (int mi = 0; mi < 4; mi++)
#pragma unroll
            for (int ni = 0; ni < 4; ni++)
                acc[mi][ni] = __builtin_amdgcn_mfma_f32_16x16x32_bf16(fa[mi], fb[ni], acc[mi][ni], 0, 0, 0);
        __syncthreads();
    }
    const int r0 = (lane >> 4) * 4;
    const int cc0 = lane & 15;
#pragma unroll
    for (int mi = 0; mi < 4; mi++) {
#pragma unroll
        for (int ni = 0; ni < 4; ni++) {
            size_t rr = (size_t)(mt * 128 + wm * 64 + mi * 16 + r0);
            int cc = nt * 128 + wn * 64 + ni * 16 + cc0;
#pragma unroll
            for (int r = 0; r < 4; r++) Cout[(rr + r) * 1024 + cc] = acc[mi][ni][r];
        }
    }
}

// ---------------- per-chunk A_j and plast_j (tier-3 only) -------------------
template <typename VT>
__global__ __launch_bounds__(64) void ka_k(const int* __restrict__ ts,
                                           const float* __restrict__ gammap,
                                           const VT* values,
                                           float* __restrict__ Aws,
                                           float* __restrict__ plastWs) {
    __shared__ float s_k0[64], s_k1[64];
    int bid = blockIdx.x;
    int j = bid & 127;
    int h = (bid >> 7) & 7;
    int b = bid >> 10;
    int l = threadIdx.x;
    int s = j * 64 + l;
    float iv = 1.f; double invb = 1.0;
    for (int i = 0; i < h; i++) { iv *= 10.f; invb *= 0.1; }
    float sf = (float)(6.283185307179586 * invb);
    float gp = gammap[h];
    float gm = 1.f / (1.f + expf(-gp));
    float lg = logf(fmaxf(gm, 1e-6f));
    int its = ts[b * SS + s];
    int itp = (s > 0) ? ts[b * SS + s - 1] : its;
    int dstep = its - itp; if (dstep < 0) dstep = 0;
    float dec = expf(lg * ((float)dstep * sf));
    float p = fmaxf(dec, EPSF);
#pragma unroll
    for (int off = 1; off < 64; off <<= 1) {
        float o = __shfl_up(p, off, 64);
        if (l >= off) p *= o;
    }
    float plast = __shfl(p, 63, 64);
    float swv = plast / fmaxf(p, EPSF);
    float tk = fmodf((float)its, iv) * sf;
    s_k0[l] = cosf(tk) * swv;
    s_k1[l] = sinf(tk) * swv;
    __syncthreads();
    if (l == 0) {
        plastWs[(b * CC + h) * NCH + j] = plast;
        plastWs[(b * CC + h + 8) * NCH + j] = plast;
    }
    int e = l;
#pragma unroll
    for (int cc2 = 0; cc2 < 2; ++cc2) {
        int c = h + cc2 * 8;
        const VT* vb = values + ((size_t)b * SS + (size_t)j * 64) * DIMD + c * 64 + e;
        float a0 = 0.f, a1 = 0.f;
#pragma unroll 8
        for (int m = 0; m < 64; ++m) {
            float vv = (float)vb[(size_t)m * DIMD];
            a0 += s_k0[m] * vv;
            a1 += s_k1[m] * vv;
        }
        float* ab = Aws + ((size_t)(b * CC + c) * NCH + j) * 128;
        ab[e] = a0;
        ab[64 + e] = a1;
    }
}

// ---------------- inter-chunk linear scan (LDS bulk-staged) -----------------
__global__ __launch_bounds__(128) void kb_k(const float* __restrict__ Aws,
                                            const float* __restrict__ plastWs,
                                            float* __restrict__ Sws) {
    __shared__ float pl[NCH];
    __shared__ __align__(16) float sa[NCH][128];       // 64 KiB
    const int bc = blockIdx.x;
    const int t = threadIdx.x;
    const int wv = t >> 6;          // wave id (uniform per wave)
    const int ln = t & 63;
    pl[t] = plastWs[bc * NCH + t];
    const float* ab = Aws + (size_t)bc * NCH * 128;
#pragma unroll
    for (int i = 0; i < 32; ++i) {
        const int row = i * 4 + wv * 2;
        GLOAD_LDS16(ab + (size_t)row * 128 + ln * 4, (char*)&sa[row][0] + ln * 16);
    }
    asm volatile("s_waitcnt vmcnt(0)" ::: "memory");
    __syncthreads();
    float st = 0.f;
    float* sb = Sws + (size_t)bc * NCH * 128 + t;
#pragma unroll 4
    for (int j = 0; j < NCH; ++j) {
        sb[(size_t)j * 128] = st;
        st = st * pl[j] + sa[j][t];
    }
}

// ---------------- per-chunk output, MFMA version (tier-1, bf16 V) -----------
__global__ __launch_bounds__(256, 2) void kc2_k(const int* __restrict__ ts,
                                                const int* __restrict__ nts,
                                                const float* __restrict__ gammap,
                                                const float* __restrict__ alphap,
                                                const float* __restrict__ betap,
                                                const bh* __restrict__ values,
                                                const float* __restrict__ Sws,
                                                float* __restrict__ outp) {
    __shared__ __align__(16) bh vt[8][4096];       // 8 regions x 8 KiB
    __shared__ float s_b0[4][64], s_b1[4][64];     // per-h (wave)
    __shared__ float s_a0[8][64], s_a1[8][64];     // per region (w,cc)
    __shared__ float s_st0[8][64], s_st1[8][64];   // per region

    const int bid = blockIdx.x;
    const int g = bid & 1;
    const int j = (bid >> 1) & 127;
    const int b = bid >> 8;
    const int tid = threadIdx.x, lane = tid & 63, w = tid >> 6;
    const int h = g * 4 + w;
    const int s = j * 64 + lane;

    const int its = ts[b * SS + s];
    const int itp = (s > 0) ? ts[b * SS + s - 1] : its;
    const int inx = nts[b * SS + s];
    const float* swp0 = Sws + ((size_t)(b * CC + h) * NCH + j) * 128;
    const float* swp1 = Sws + ((size_t)(b * CC + h + 8) * NCH + j) * 128;
    const float st00 = swp0[lane], st10 = swp0[64 + lane];
    const float st01 = swp1[lane], st11 = swp1[64 + lane];
    const float al0 = alphap[h], al1 = alphap[h + 8];
    const float be0 = betap[h], be1 = betap[h + 8];
    const float gp = gammap[h];

    const bh* gv0 = values + ((size_t)b * SS + (size_t)j * 64 + (lane >> 1)) * DIMD
                    + h * 64 + (lane & 1) * 8;
    const bh* gv1 = gv0 + 512;                     // channel h+8
    char* lc0 = (char*)&vt[w * 2][0] + lane * 16;
    char* lc1 = (char*)&vt[w * 2 + 1][0] + lane * 16;
#pragma unroll
    for (int mh = 0; mh < 2; ++mh)
#pragma unroll
        for (int pp = 0; pp < 4; ++pp)
            GLOAD_LDS16(gv0 + mh * 32 * DIMD + pp * 16, lc0 + pp * 2048 + mh * 1024);
#pragma unroll
    for (int mh = 0; mh < 2; ++mh)
#pragma unroll
        for (int pp = 0; pp < 4; ++pp)
            GLOAD_LDS16(gv1 + mh * 32 * DIMD + pp * 16, lc1 + pp * 2048 + mh * 1024);

    float iv = 1.f; double invb = 1.0;
    for (int i = 0; i < h; i++) { iv *= 10.f; invb *= 0.1; }
    const float sf = (float)(6.283185307179586 * invb);
    const float gm = 1.f / (1.f + expf(-gp));
    const float lg = logf(fmaxf(gm, 1e-6f));
    int dstep = its - itp; if (dstep < 0) dstep = 0;
    const float dec = expf(lg * ((float)dstep * sf));
    float p = fmaxf(dec, EPSF);
#pragma unroll
    for (int off = 1; off < 64; off <<= 1) {
        float o = __shfl_up(p, off, 64);
        if (lane >= off) p *= o;
    }
    const float ipv = 1.f / fmaxf(p, EPSF);
    const float tk = fmodf((float)its, iv) * sf;
    const float k0 = cosf(tk), k1 = sinf(tk);
    s_b0[w][lane] = k0 * ipv;
    s_b1[w][lane] = k1 * ipv;
    const float tq = fmodf((float)inx, iv) * sf;
    int dq = inx - its; if (dq < 0) dq = 0;
    const float qd = expf(lg * ((float)dq * sf));
    const float sq = sinf(tq), cq = cosf(tq);
    const int r0i = w * 2, r1i = w * 2 + 1;
    s_a0[r0i][lane] = sq * qd * p * al0;  s_a1[r0i][lane] = -cq * qd * p * al0;
    s_a0[r1i][lane] = cq * qd * p * al1;  s_a1[r1i][lane] = sq * qd * p * al1;
    s_st0[r0i][lane] = st00; s_st1[r0i][lane] = st10;
    s_st0[r1i][lane] = st01; s_st1[r1i][lane] = st11;
    asm volatile("s_waitcnt lgkmcnt(0)" ::: "memory");

    fx4 rb0[2][2], rb1[2][2];
#pragma unroll
    for (int ks = 0; ks < 2; ++ks) {
        const int m0 = ks * 32 + (lane >> 4) * 8;
        rb0[ks][0] = *reinterpret_cast<const fx4*>(&s_b0[w][m0]);
        rb0[ks][1] = *reinterpret_cast<const fx4*>(&s_b0[w][m0 + 4]);
        rb1[ks][0] = *reinterpret_cast<const fx4*>(&s_b1[w][m0]);
        rb1[ks][1] = *reinterpret_cast<const fx4*>(&s_b1[w][m0 + 4]);
    }

#pragma unroll
    for (int cc = 0; cc < 2; ++cc) {
        const int reg = w * 2 + cc;
        const int c = h + cc * 8;
        const char* vbase2 = (const char*)&vt[reg][0];

        bhx8 pa[4][2];
#pragma unroll
        for (int mi = 0; mi < 4; ++mi) {
            const int l = mi * 16 + (lane & 15);
            const float a0l = s_a0[reg][l];
            const float a1l = s_a1[reg][l];
#pragma unroll
            for (int ks = 0; ks < 2; ++ks) {
                if (mi * 16 + 16 <= ks * 32) continue;
                const bool full = (mi * 16 >= ks * 32 + 32);
                bhx8 v;
#pragma unroll
                for (int jj = 0; jj < 8; ++jj) {
                    const int m = ks * 32 + (lane >> 4) * 8 + jj;
                    const float b0m = rb0[ks][jj >> 2][jj & 3];
                    const float b1m = rb1[ks][jj >> 2][jj & 3];
                    const float val = a0l * b0m + a1l * b1m;
                    v[jj] = (full || l >= m) ? (bh)val : (bh)0.f;
                }
                pa[mi][ks] = v;
            }
        }

        if (cc == 0) { asm volatile("s_waitcnt vmcnt(8)" ::: "memory"); }
        else         { asm volatile("s_waitcnt vmcnt(0)" ::: "memory"); }

        const uint32_t tb = LDSA(vbase2) + ((lane >> 4) << 8) + ((lane & 15) << 3);
        bhx8 pb[4][2];
#pragma unroll
        for (int ni = 0; ni < 4; ++ni)
#pragma unroll
            for (int ks = 0; ks < 2; ++ks) {
                const uint32_t a2 = tb + ni * 2048 + ks * 1024;
                u32x2 lo, hi;
                asm volatile("ds_read_b64_tr_b16 %0, %2 offset:0\n\t"
                             "ds_read_b64_tr_b16 %1, %2 offset:128"
                             : "=&v"(lo), "=&v"(hi) : "v"(a2));
                union { u32x2 u[2]; bhx8 f; } u_;
                u_.u[0] = lo; u_.u[1] = hi;
                pb[ni][ks] = u_.f;
            }
        asm volatile("s_waitcnt lgkmcnt(0)" ::: "memory");
        SB();

        fx4 acc[4][4];
#pragma unroll
        for (int mi = 0; mi < 4; ++mi)
#pragma unroll
            for (int ni = 0; ni < 4; ++ni)
#pragma unroll
                for (int r = 0; r < 4; ++r) acc[mi][ni][r] = 0.f;
        __builtin_amdgcn_s_setprio(1);
#pragma unroll
        for (int ks = 0; ks < 2; ++ks)
#pragma unroll
            for (int mi = 0; mi < 4; ++mi) {
                if (mi * 16 + 16 <= ks * 32) continue;
#pragma unroll
                for (int ni = 0; ni < 4; ++ni)
                    acc[mi][ni] = __builtin_amdgcn_mfma_f32_16x16x32_bf16(
                        pa[mi][ks], pb[ni][ks], acc[mi][ni], 0, 0, 0);
            }
        __builtin_amdgcn_s_setprio(0);
        SB();

        float st0e[4], st1e[4];
#pragma unroll
        for (int ni = 0; ni < 4; ++ni) {
            st0e[ni] = s_st0[reg][ni * 16 + (lane & 15)];
            st1e[ni] = s_st1[reg][ni * 16 + (lane & 15)];
        }
        const float bev = (cc == 0) ? be0 : be1;
        float* ob = outp + ((size_t)b * SS + (size_t)j * 64) * DIMD + c * 64 + (lane & 15);
#pragma unroll
        for (int mi = 0; mi < 4; ++mi)
#pragma unroll
            for (int r = 0; r < 4; ++r) {
                const int l = mi * 16 + ((lane >> 4) << 2) + r;
                const float a0l = s_a0[reg][l];
                const float a1l = s_a1[reg][l];
#pragma unroll
                for (int ni = 0; ni < 4; ++ni) {
                    const float vv = (float)*reinterpret_cast<const bh*>(
                        vbase2 + ni * 2048 + (mi * 4 + (lane >> 4)) * 128 + r * 32 + ((lane & 15) << 1));
                    const float o = acc[mi][ni][r] + a0l * st0e[ni] + a1l * st1e[ni] + bev * vv;
                    ob[(size_t)l * DIMD + ni * 16] = o;
                }
            }
    }
}

// ---------------- per-chunk output (f32 fallback, tiers 2/3) ----------------
template <typename VT>
__global__ __launch_bounds__(256) void kc_k(const int* __restrict__ ts,
                                            const int* __restrict__ nts,
                                            const float* __restrict__ gammap,
                                            const float* __restrict__ alphap,
                                            const float* __restrict__ betap,
                                            const VT* values,     // may alias outp
                                            const float* __restrict__ Sws,
                                            float* outp) {
    __shared__ float vsm[64][64];
    __shared__ float s_p[64], s_ip[64], s_k0[64], s_k1[64], s_q0[64], s_q1[64];
    __shared__ float s_st[128];
    int bid = blockIdx.x;
    int j = bid & 127;
    int c = (bid >> 7) & 15;
    int b = bid >> 11;
    int h = c & 7;
    int tid = threadIdx.x;
    if (tid < 64) {
        int l = tid;
        int s = j * 64 + l;
        float iv = 1.f; double invb = 1.0;
        for (int i = 0; i < h; i++) { iv *= 10.f; invb *= 0.1; }
        float sf = (float)(6.283185307179586 * invb);
        float gp = gammap[h];
        float gm = 1.f / (1.f + expf(-gp));
        float lg = logf(fmaxf(gm, 1e-6f));
        int its = ts[b * SS + s];
        int itp = (s > 0) ? ts[b * SS + s - 1] : its;
        int dstep = its - itp; if (dstep < 0) dstep = 0;
        float dec = expf(lg * ((float)dstep * sf));
        float p = fmaxf(dec, EPSF);
#pragma unroll
        for (int off = 1; off < 64; off <<= 1) {
            float o = __shfl_up(p, off, 64);
            if (l >= off) p *= o;
        }
        s_p[l] = p;
        s_ip[l] = 1.f / fmaxf(p, EPSF);
        float tk = fmodf((float)its, iv) * sf;
        s_k0[l] = cosf(tk);
        s_k1[l] = sinf(tk);
        int inx = nts[b * SS + s];
        float tq = fmodf((float)inx, iv) * sf;
        int dq = inx - its; if (dq < 0) dq = 0;
        float qd = expf(lg * ((float)dq * sf));
        float sq = sinf(tq), cq2 = cosf(tq);
        s_q0[l] = (c < 8) ? sq * qd : cq2 * qd;
        s_q1[l] = (c < 8) ? (-cq2 * qd) : sq * qd;
    }
    const VT* vbase = values + ((size_t)b * SS + (size_t)j * 64) * DIMD + c * 64;
#pragma unroll
    for (int i = 0; i < 2; ++i) {
        int f = tid + i * 256;
        int row = f >> 3;
        int c8 = f & 7;
        if constexpr (sizeof(VT) == 2) {
            bhx8 v8 = *reinterpret_cast<const bhx8*>(vbase + (size_t)row * DIMD + c8 * 8);
#pragma unroll
            for (int r = 0; r < 8; ++r) vsm[row][c8 * 8 + r] = (float)v8[r];
        } else {
            *reinterpret_cast<float4*>(&vsm[row][c8 * 8]) =
                *reinterpret_cast<const float4*>(vbase + (size_t)row * DIMD + c8 * 8);
            *reinterpret_cast<float4*>(&vsm[row][c8 * 8 + 4]) =
                *reinterpret_cast<const float4*>(vbase + (size_t)row * DIMD + c8 * 8 + 4);
        }
    }
    if (tid < 128) {
        s_st[tid] = Sws[((size_t)(b * CC + c) * NCH + j) * 128 + tid];
    }
    __syncthreads();
    int l = tid >> 2, eg = tid & 3;
    float acc[16];
#pragma unroll
    for (int i = 0; i < 16; i++) acc[i] = 0.f;
    float q0 = s_q0[l], q1 = s_q1[l], pl_ = s_p[l];
    for (int m = 0; m <= l; ++m) {
        float wgt = (q0 * s_k0[m] + q1 * s_k1[m]) * (pl_ * s_ip[m]);
        const float* vr = &vsm[m][eg * 16];
#pragma unroll
        for (int i = 0; i < 16; i++) acc[i] += wgt * vr[i];
    }
    float al = alphap[c], be = betap[c];
    float* ob = outp + ((size_t)b * SS + (size_t)j * 64 + l) * DIMD + c * 64 + eg * 16;
    const float* st0 = &s_st[eg * 16];
    const float* st1 = &s_st[64 + eg * 16];
#pragma unroll
    for (int i2 = 0; i2 < 4; i2++) {
        float4 vv = *reinterpret_cast<const float4*>(&vsm[l][eg * 16 + i2 * 4]);
        float4 o4;
        const float* vvp = (const float*)&vv;
        float* o4p = (float*)&o4;
#pragma unroll
        for (int r = 0; r < 4; r++) {
            int i = i2 * 4 + r;
            float prevt = pl_ * (q0 * st0[i] + q1 * st1[i]);
            o4p[r] = (prevt + acc[i]) * al + vvp[r] * be;
        }
        *reinterpret_cast<float4*>(ob + i2 * 4) = o4;
    }
}

extern "C" void kernel_launch(void* const* d_in, const int* in_sizes, int n_in,
                              void* d_out, int out_size, void* d_ws, size_t ws_size,
                              hipStream_t stream) {
    const float* inputs = (const float*)d_in[0];
    const float* Wv     = (const float*)d_in[1];
    const float* gammap = (const float*)d_in[2];
    const float* alphap = (const float*)d_in[3];
    const float* betap  = (const float*)d_in[4];
    const int*   ts     = (const int*)d_in[5];
    const int*   nts    = (const int*)d_in[6];
    float* outp = (float*)d_out;
    char* ws = (char*)d_ws;

    float* Aws     = (float*)ws;                    // 4 MiB
    float* plastWs = (float*)(ws + 4194304);        // 32 KiB
    float* Sws     = (float*)(ws + 4227072);        // 4 MiB
    const size_t base   = 8421376;
    const size_t wbytes = 2097152;                  // Wbf 2 MiB
    const size_t vbytes = 67108864;                 // Vbf 64 MiB

    if (ws_size >= base + wbytes + vbytes) {
        // tier 1: fused cvt+GEMM+ka (f32 A direct) -> bf16 values in workspace
        bh* Wbf = (bh*)(ws + base);
        bh* Vbf = (bh*)(ws + base + wbytes);
        cvt_k<<<512, 256, 0, stream>>>(Wv, Wbf, 131072);
        gemm256f3<bh><<<512, 512, 0, stream>>>(inputs, Wbf, Vbf, ts, gammap, Aws, plastWs);
        kb_k<<<64, 128, 0, stream>>>(Aws, plastWs, Sws);
        kc2_k<<<1024, 256, 0, stream>>>(ts, nts, gammap, alphap, betap, Vbf, Sws, outp);
    } else if (ws_size >= base + wbytes) {
        // tier 2: fused cvt+GEMM+ka -> f32 values staged in d_out
        bh* Wbf = (bh*)(ws + base);
        cvt_k<<<512, 256, 0, stream>>>(Wv, Wbf, 131072);
        gemm256f3<float><<<512, 512, 0, stream>>>(inputs, Wbf, outp, ts, gammap, Aws, plastWs);
        kb_k<<<64, 128, 0, stream>>>(Aws, plastWs, Sws);
        kc_k<float><<<8192, 256, 0, stream>>>(ts, nts, gammap, alphap, betap, outp, Sws, outp);
    } else {
        // tier 3: legacy path
        gemm_k<<<2048, 256, 0, stream>>>(inputs, Wv, outp);
        ka_k<float><<<4096, 64, 0, stream>>>(ts, gammap, outp, Aws, plastWs);
        kb_k<<<64, 128, 0, stream>>>(Aws, plastWs, Sws);
        kc_k<float><<<8192, 256, 0, stream>>>(ts, nts, gammap, alphap, betap, outp, Sws, outp);
    }
}

// Round 9
// 170.211 us; speedup vs baseline: 1.2995x; 1.2995x over previous
//
#include <hip/hip_runtime.h>
#include <stdint.h>

#define SS   8192
#define DIMD 1024
#define NCH  128
#define CC   16
#define EPSF 1e-8f

typedef __bf16 bh;
typedef bh    bhx4 __attribute__((ext_vector_type(4)));
typedef bh    bhx8 __attribute__((ext_vector_type(8)));
typedef float fx4  __attribute__((ext_vector_type(4)));
typedef unsigned int u32x2 __attribute__((ext_vector_type(2)));

#define GLOAD_LDS16(g, l) __builtin_amdgcn_global_load_lds(                    \
    (const __attribute__((address_space(1))) uint32_t*)(g),                    \
    (__attribute__((address_space(3))) uint32_t*)(l), 16, 0, 0)

#define LDSA(p) ((uint32_t)(uintptr_t)(const __attribute__((address_space(3))) char*)(const char*)(p))

#define SB() __builtin_amdgcn_sched_barrier(0)
#define PRE_BAR()  do { SB(); __builtin_amdgcn_s_barrier(); SB();              \
                        __builtin_amdgcn_s_setprio(1); } while (0)
#define POST_BAR() do { __builtin_amdgcn_s_setprio(0); SB();                   \
                        __builtin_amdgcn_s_barrier(); SB(); } while (0)

// ---------------- merged f32 -> bf16 convert (Wv + inputs, one launch) ------
// blocks [0,512): Wv (131072 x 8 floats); blocks [512,16896): inputs.
__global__ __launch_bounds__(256) void cvt2_k(const float* __restrict__ srcA,
                                              const float* __restrict__ srcW,
                                              bh* __restrict__ dstA,
                                              bh* __restrict__ dstW) {
    const int i = blockIdx.x * 256 + threadIdx.x;
    const float* src;
    bh* dst;
    int idx;
    if (i < 131072) { src = srcW; dst = dstW; idx = i; }
    else            { src = srcA; dst = dstA; idx = i - 131072; }
    const float4 a = reinterpret_cast<const float4*>(src)[idx * 2];
    const float4 b = reinterpret_cast<const float4*>(src)[idx * 2 + 1];
    bhx8 o;
    o[0] = (bh)a.x; o[1] = (bh)a.y; o[2] = (bh)a.z; o[3] = (bh)a.w;
    o[4] = (bh)b.x; o[5] = (bh)b.y; o[6] = (bh)b.z; o[7] = (bh)b.w;
    reinterpret_cast<bhx8*>(dst)[idx] = o;
}

// ---------------- bf16 GEMM + fused ka: C = A @ Bw^T, A_j, plast_j ----------
// (exact Round-5 best-measured version: plain prologue, ka in epilogue with
//  vectorized fx4 w-reads; 4-phase BK=64 counted-vmcnt schedule)
template <typename VT>
__global__ __launch_bounds__(512, 2) void gemm256a(const bh* __restrict__ A,
                                                   const bh* __restrict__ Bw,
                                                   VT* __restrict__ C,
                                                   const int* __restrict__ tsp,
                                                   const float* __restrict__ gammap,
                                                   float* __restrict__ Aws,
                                                   float* __restrict__ plastWs) {
    __shared__ __align__(16) char ldsraw[131072];
    const int lb = blockIdx.x;
    const int logical = (lb & 7) * 64 + (lb >> 3);   // XCD-chunked, bijective (512 wg)
    const int mt = logical >> 2;                     // 128 m-tiles
    const int nt = logical & 3;                      // 4 n-tiles
    const int tid = threadIdx.x, lane = tid & 63, w = tid >> 6;
    const int wm = w >> 2, wn = w & 3;

    fx4 acc[8][4];
#pragma unroll
    for (int i = 0; i < 8; ++i)
#pragma unroll
        for (int j = 0; j < 4; ++j)
#pragma unroll
            for (int r = 0; r < 4; ++r) acc[i][j][r] = 0.f;

    const int kgo = ((tid & 3) ^ ((tid >> 3) & 3)) << 3;   // element offset
    const bh* gA0 = A  + (size_t)(mt * 256 + (tid >> 2)) * DIMD + kgo;
    const bh* gB0 = Bw + (size_t)(nt * 256 + (tid >> 2)) * DIMD + kgo;

#define STAGE_U(kt, obase, g, h)                                               \
    { char* lp = ldsraw + ((((kt) & 1) * 65536) + (obase) + (h) * 16384) + tid * 16; \
      const bh* gp = (g) + (kt) * 64 + (h) * 32;                               \
      GLOAD_LDS16(gp, lp);                                                     \
      GLOAD_LDS16(gp + 131072, lp + 8192); }

    const int rAb = wm * 128 + (lane & 15);
    const int rBb = wn * 64 + (lane & 15);
    const int s_swz = (lane >> 4) ^ (((lane & 15) >> 1) & 3);
    const int offA = rAb * 64 + s_swz * 16;
    const int offB = rBb * 64 + s_swz * 16;

    STAGE_U(0, 0, gA0, 0); STAGE_U(0, 32768, gB0, 0);
    STAGE_U(0, 0, gA0, 1); STAGE_U(0, 32768, gB0, 1);
    STAGE_U(1, 0, gA0, 0); STAGE_U(1, 32768, gB0, 0);
    STAGE_U(1, 0, gA0, 1); STAGE_U(1, 32768, gB0, 1);
    asm volatile("s_waitcnt vmcnt(8)" ::: "memory");   // tile0 landed
    SB(); __builtin_amdgcn_s_barrier(); SB();

#pragma unroll 2
    for (int t = 0; t < 16; ++t) {
        const int buf = t & 1;
        const char* pA0 = ldsraw + buf * 65536 + offA;            // A kh0
        const char* pB0 = ldsraw + buf * 65536 + 32768 + offB;    // B kh0
        bhx8 fa[4], fb[4];

        // ---- G1: (mq0, k0) ----
#pragma unroll
        for (int i = 0; i < 4; ++i) fa[i] = *reinterpret_cast<const bhx8*>(pA0 + i * 1024);
#pragma unroll
        for (int j = 0; j < 4; ++j) fb[j] = *reinterpret_cast<const bhx8*>(pB0 + j * 1024);
        if (t >= 1 && t <= 14) STAGE_U(t + 1, 0, gA0, 1);
        PRE_BAR();
#pragma unroll
        for (int i = 0; i < 4; ++i)
#pragma unroll
            for (int j = 0; j < 4; ++j)
                acc[i][j] = __builtin_amdgcn_mfma_f32_16x16x32_bf16(fa[i], fb[j], acc[i][j], 0, 0, 0);
        POST_BAR();

        // ---- G2: (mq1, k0) ----
#pragma unroll
        for (int i = 0; i < 4; ++i) fa[i] = *reinterpret_cast<const bhx8*>(pA0 + (4 + i) * 1024);
        if (t <= 13) STAGE_U(t + 2, 32768, gB0, 0);
        PRE_BAR();
#pragma unroll
        for (int i = 0; i < 4; ++i)
#pragma unroll
            for (int j = 0; j < 4; ++j)
                acc[4 + i][j] = __builtin_amdgcn_mfma_f32_16x16x32_bf16(fa[i], fb[j], acc[4 + i][j], 0, 0, 0);
        POST_BAR();

        // ---- G3: (mq0, k1) ----
#pragma unroll
        for (int i = 0; i < 4; ++i) fa[i] = *reinterpret_cast<const bhx8*>(pA0 + 16384 + i * 1024);
#pragma unroll
        for (int j = 0; j < 4; ++j) fb[j] = *reinterpret_cast<const bhx8*>(pB0 + 16384 + j * 1024);
        if (t <= 13) STAGE_U(t + 2, 0, gA0, 0);
        PRE_BAR();
#pragma unroll
        for (int i = 0; i < 4; ++i)
#pragma unroll
            for (int j = 0; j < 4; ++j)
                acc[i][j] = __builtin_amdgcn_mfma_f32_16x16x32_bf16(fa[i], fb[j], acc[i][j], 0, 0, 0);
        POST_BAR();

        // ---- G4: (mq1, k1) ----
#pragma unroll
        for (int i = 0; i < 4; ++i) fa[i] = *reinterpret_cast<const bhx8*>(pA0 + 16384 + (4 + i) * 1024);
        if (t <= 13) STAGE_U(t + 2, 32768, gB0, 1);
        PRE_BAR();
#pragma unroll
        for (int i = 0; i < 4; ++i)
#pragma unroll
            for (int j = 0; j < 4; ++j)
                acc[4 + i][j] = __builtin_amdgcn_mfma_f32_16x16x32_bf16(fa[i], fb[j], acc[4 + i][j], 0, 0, 0);
        __builtin_amdgcn_s_setprio(0);
        if (t < 14)       { asm volatile("s_waitcnt vmcnt(6)" ::: "memory"); }
        else if (t == 14) { asm volatile("s_waitcnt vmcnt(0)" ::: "memory"); }
        SB(); __builtin_amdgcn_s_barrier(); SB();
    }
#undef STAGE_U

    // ---- C-store: col = lane&15, row = (lane>>4)*4 + r (m89-verified) ----
    const int r0 = (lane >> 4) * 4;
    const int c0 = lane & 15;
#pragma unroll
    for (int mi = 0; mi < 8; ++mi) {
#pragma unroll
        for (int ni = 0; ni < 4; ++ni) {
            const size_t m = (size_t)(mt * 256 + wm * 128 + mi * 16 + r0);
            const int    n = nt * 256 + wn * 64 + ni * 16 + c0;
#pragma unroll
            for (int r = 0; r < 4; ++r) {
                if constexpr (sizeof(VT) == 2)
                    C[(m + r) * DIMD + n] = (bh)acc[mi][ni][r];
                else
                    C[(m + r) * DIMD + n] = acc[mi][ni][r];
            }
        }
    }

    // ================= fused ka epilogue =================
    float* wlds = (float*)ldsraw + w * 256;
    const int b_ = mt >> 5;
    const int j0 = (mt & 31) * 4;
    const int c_ = nt * 4 + wn;
    const int h_ = c_ & 7;
    float iv = 1.f; double invb = 1.0;
    for (int i = 0; i < h_; i++) { iv *= 10.f; invb *= 0.1; }
    const float sf = (float)(6.283185307179586 * invb);
    const float gm = 1.f / (1.f + expf(-gammap[h_]));
    const float lg = logf(fmaxf(gm, 1e-6f));

#pragma unroll
    for (int jl = 0; jl < 2; ++jl) {
        const int jg = j0 + wm * 2 + jl;
        const int sl = jg * 64 + lane;                 // batch-local index
        const int its = tsp[b_ * SS + sl];
        const int itp = (sl > 0) ? tsp[b_ * SS + sl - 1] : its;
        int dstep = its - itp; if (dstep < 0) dstep = 0;
        const float dec = expf(lg * ((float)dstep * sf));
        float p = fmaxf(dec, EPSF);
#pragma unroll
        for (int off = 1; off < 64; off <<= 1) {
            float o = __shfl_up(p, off, 64);
            if (lane >= off) p *= o;
        }
        const float plast = __shfl(p, 63, 64);
        const float swv = plast / fmaxf(p, EPSF);
        const float tk = fmodf((float)its, iv) * sf;
        wlds[jl * 128 + lane]      = cosf(tk) * swv;
        wlds[jl * 128 + 64 + lane] = sinf(tk) * swv;
        if (lane == 0) plastWs[(size_t)(b_ * CC + c_) * NCH + jg] = plast;
    }
    // wave-private LDS: own writes ordered before own reads via lgkmcnt
    asm volatile("s_waitcnt lgkmcnt(0)" ::: "memory");

#pragma unroll
    for (int jl = 0; jl < 2; ++jl) {
        const int jg = j0 + wm * 2 + jl;
        float* ab = Aws + ((size_t)(b_ * CC + c_) * NCH + jg) * 128;
        // vectorized w-reads: rows ml = q*16 + (lane>>4)*4 + r, r contiguous
        fx4 w0q[4], w1q[4];
        const int gb = ((lane >> 4) << 2);
#pragma unroll
        for (int q = 0; q < 4; ++q) {
            w0q[q] = *reinterpret_cast<const fx4*>(&wlds[jl * 128 + q * 16 + gb]);
            w1q[q] = *reinterpret_cast<const fx4*>(&wlds[jl * 128 + 64 + q * 16 + gb]);
        }
#pragma unroll
        for (int ni = 0; ni < 4; ++ni) {
            float pa0 = 0.f, pa1 = 0.f;
#pragma unroll
            for (int q = 0; q < 4; ++q)
#pragma unroll
                for (int r = 0; r < 4; ++r) {
                    const float av = acc[jl * 4 + q][ni][r];
                    pa0 += w0q[q][r] * av;
                    pa1 += w1q[q][r] * av;
                }
            pa0 += __shfl_xor(pa0, 16, 64); pa0 += __shfl_xor(pa0, 32, 64);
            pa1 += __shfl_xor(pa1, 16, 64); pa1 += __shfl_xor(pa1, 32, 64);
            const int e = ni * 16 + (lane & 15);
            const int grp = lane >> 4;
            if (grp == 0)      ab[e] = pa0;
            else if (grp == 1) ab[64 + e] = pa1;
        }
    }
}

// ---------------- legacy f32 GEMM (tier-3 fallback) -------------------------
__global__ __launch_bounds__(256) void gemm_k(const float* __restrict__ Ain,
                                              const float* __restrict__ Win,
                                              float* __restrict__ Cout) {
    __shared__ __align__(16) char ldsraw[20480];
    char* ldsA = ldsraw;
    char* ldsB = ldsraw + 10240;
    const int tid = threadIdx.x;
    const int lane = tid & 63;
    const int w = tid >> 6;
    const int wm = w >> 1, wn = w & 1;
    const int bid = blockIdx.x;
    const int mt = bid >> 3;
    const int nt = bid & 7;
    const size_t Abase = (size_t)mt * 128 * 1024;
    const size_t Bbase = (size_t)nt * 128 * 1024;
    fx4 acc[4][4];
#pragma unroll
    for (int i = 0; i < 4; i++)
#pragma unroll
        for (int j2 = 0; j2 < 4; j2++)
#pragma unroll
            for (int r = 0; r < 4; r++) acc[i][j2][r] = 0.f;
    const int srow0 = tid >> 3;
    const int sc16 = tid & 7;
    for (int kt = 0; kt < 32; ++kt) {
        const int k0 = kt * 32;
#pragma unroll
        for (int jj = 0; jj < 4; jj++) {
            int row = srow0 + jj * 32;
            const float4 va = *reinterpret_cast<const float4*>(Ain + Abase + (size_t)row * 1024 + k0 + sc16 * 4);
            const float4 vb = *reinterpret_cast<const float4*>(Win + Bbase + (size_t)row * 1024 + k0 + sc16 * 4);
            bhx4 ba, bb2;
            ba[0] = (bh)va.x; ba[1] = (bh)va.y; ba[2] = (bh)va.z; ba[3] = (bh)va.w;
            bb2[0] = (bh)vb.x; bb2[1] = (bh)vb.y; bb2[2] = (bh)vb.z; bb2[3] = (bh)vb.w;
            *reinterpret_cast<bhx4*>(ldsA + row * 80 + sc16 * 8) = ba;
            *reinterpret_cast<bhx4*>(ldsB + row * 80 + sc16 * 8) = bb2;
        }
        __syncthreads();
        bhx8 fa[4], fb[4];
        const int kb = (lane >> 4) * 16;
        const int rA = wm * 64 + (lane & 15);
        const int rB = wn * 64 + (lane & 15);
#pragma unroll
        for (int mi = 0; mi < 4; mi++) fa[mi] = *reinterpret_cast<const bhx8*>(ldsA + (rA + mi * 16) * 80 + kb);
#pragma unroll
        for (int ni = 0; ni < 4; ni++) fb[ni] = *reinterpret_cast<const bhx8*>(ldsB + (rB + ni * 16) * 80 + kb);
#pragma unroll
        for (int mi = 0; mi < 4; mi++)
#pragma unroll
            for (int ni = 0; ni < 4; ni++)
                acc[mi][ni] = __builtin_amdgcn_mfma_f32_16x16x32_bf16(fa[mi], fb[ni], acc[mi][ni], 0, 0, 0);
        __syncthreads();
    }
    const int r0 = (lane >> 4) * 4;
    const int cc0 = lane & 15;
#pragma unroll
    for (int mi = 0; mi < 4; mi++) {
#pragma unroll
        for (int ni = 0; ni < 4; ni++) {
            size_t rr = (size_t)(mt * 128 + wm * 64 + mi * 16 + r0);
            int cc = nt * 128 + wn * 64 + ni * 16 + cc0;
#pragma unroll
            for (int r = 0; r < 4; r++) Cout[(rr + r) * 1024 + cc] = acc[mi][ni][r];
        }
    }
}

// ---------------- per-chunk A_j and plast_j (tier-3 only) -------------------
template <typename VT>
__global__ __launch_bounds__(64) void ka_k(const int* __restrict__ ts,
                                           const float* __restrict__ gammap,
                                           const VT* values,
                                           float* __restrict__ Aws,
                                           float* __restrict__ plastWs) {
    __shared__ float s_k0[64], s_k1[64];
    int bid = blockIdx.x;
    int j = bid & 127;
    int h = (bid >> 7) & 7;
    int b = bid >> 10;
    int l = threadIdx.x;
    int s = j * 64 + l;
    float iv = 1.f; double invb = 1.0;
    for (int i = 0; i < h; i++) { iv *= 10.f; invb *= 0.1; }
    float sf = (float)(6.283185307179586 * invb);
    float gp = gammap[h];
    float gm = 1.f / (1.f + expf(-gp));
    float lg = logf(fmaxf(gm, 1e-6f));
    int its = ts[b * SS + s];
    int itp = (s > 0) ? ts[b * SS + s - 1] : its;
    int dstep = its - itp; if (dstep < 0) dstep = 0;
    float dec = expf(lg * ((float)dstep * sf));
    float p = fmaxf(dec, EPSF);
#pragma unroll
    for (int off = 1; off < 64; off <<= 1) {
        float o = __shfl_up(p, off, 64);
        if (l >= off) p *= o;
    }
    float plast = __shfl(p, 63, 64);
    float swv = plast / fmaxf(p, EPSF);
    float tk = fmodf((float)its, iv) * sf;
    s_k0[l] = cosf(tk) * swv;
    s_k1[l] = sinf(tk) * swv;
    __syncthreads();
    if (l == 0) {
        plastWs[(b * CC + h) * NCH + j] = plast;
        plastWs[(b * CC + h + 8) * NCH + j] = plast;
    }
    int e = l;
#pragma unroll
    for (int cc2 = 0; cc2 < 2; ++cc2) {
        int c = h + cc2 * 8;
        const VT* vb = values + ((size_t)b * SS + (size_t)j * 64) * DIMD + c * 64 + e;
        float a0 = 0.f, a1 = 0.f;
#pragma unroll 8
        for (int m = 0; m < 64; ++m) {
            float vv = (float)vb[(size_t)m * DIMD];
            a0 += s_k0[m] * vv;
            a1 += s_k1[m] * vv;
        }
        float* ab = Aws + ((size_t)(b * CC + c) * NCH + j) * 128;
        ab[e] = a0;
        ab[64 + e] = a1;
    }
}

// ---------------- inter-chunk linear scan (LDS bulk-staged) -----------------
__global__ __launch_bounds__(128) void kb_k(const float* __restrict__ Aws,
                                            const float* __restrict__ plastWs,
                                            float* __restrict__ Sws) {
    __shared__ float pl[NCH];
    __shared__ __align__(16) float sa[NCH][128];       // 64 KiB
    const int bc = blockIdx.x;
    const int t = threadIdx.x;
    const int wv = t >> 6;          // wave id (uniform per wave)
    const int ln = t & 63;
    pl[t] = plastWs[bc * NCH + t];
    const float* ab = Aws + (size_t)bc * NCH * 128;
#pragma unroll
    for (int i = 0; i < 32; ++i) {
        const int row = i * 4 + wv * 2;
        GLOAD_LDS16(ab + (size_t)row * 128 + ln * 4, (char*)&sa[row][0] + ln * 16);
    }
    asm volatile("s_waitcnt vmcnt(0)" ::: "memory");
    __syncthreads();
    float st = 0.f;
    float* sb = Sws + (size_t)bc * NCH * 128 + t;
#pragma unroll 4
    for (int j = 0; j < NCH; ++j) {
        sb[(size_t)j * 128] = st;
        st = st * pl[j] + sa[j][t];
    }
}

// ---------------- per-chunk output, MFMA version (tier-1, bf16 V) -----------
__global__ __launch_bounds__(256, 2) void kc2_k(const int* __restrict__ ts,
                                                const int* __restrict__ nts,
                                                const float* __restrict__ gammap,
                                                const float* __restrict__ alphap,
                                                const float* __restrict__ betap,
                                                const bh* __restrict__ values,
                                                const float* __restrict__ Sws,
                                                float* __restrict__ outp) {
    __shared__ __align__(16) bh vt[8][4096];       // 8 regions x 8 KiB
    __shared__ float s_b0[4][64], s_b1[4][64];     // per-h (wave)
    __shared__ float s_a0[8][64], s_a1[8][64];     // per region (w,cc)
    __shared__ float s_st0[8][64], s_st1[8][64];   // per region

    const int bid = blockIdx.x;
    const int g = bid & 1;
    const int j = (bid >> 1) & 127;
    const int b = bid >> 8;
    const int tid = threadIdx.x, lane = tid & 63, w = tid >> 6;
    const int h = g * 4 + w;
    const int s = j * 64 + lane;

    const int its = ts[b * SS + s];
    const int itp = (s > 0) ? ts[b * SS + s - 1] : its;
    const int inx = nts[b * SS + s];
    const float* swp0 = Sws + ((size_t)(b * CC + h) * NCH + j) * 128;
    const float* swp1 = Sws + ((size_t)(b * CC + h + 8) * NCH + j) * 128;
    const float st00 = swp0[lane], st10 = swp0[64 + lane];
    const float st01 = swp1[lane], st11 = swp1[64 + lane];
    const float al0 = alphap[h], al1 = alphap[h + 8];
    const float be0 = betap[h], be1 = betap[h + 8];
    const float gp = gammap[h];

    const bh* gv0 = values + ((size_t)b * SS + (size_t)j * 64 + (lane >> 1)) * DIMD
                    + h * 64 + (lane & 1) * 8;
    const bh* gv1 = gv0 + 512;                     // channel h+8
    char* lc0 = (char*)&vt[w * 2][0] + lane * 16;
    char* lc1 = (char*)&vt[w * 2 + 1][0] + lane * 16;
#pragma unroll
    for (int mh = 0; mh < 2; ++mh)
#pragma unroll
        for (int pp = 0; pp < 4; ++pp)
            GLOAD_LDS16(gv0 + mh * 32 * DIMD + pp * 16, lc0 + pp * 2048 + mh * 1024);
#pragma unroll
    for (int mh = 0; mh < 2; ++mh)
#pragma unroll
        for (int pp = 0; pp < 4; ++pp)
            GLOAD_LDS16(gv1 + mh * 32 * DIMD + pp * 16, lc1 + pp * 2048 + mh * 1024);

    float iv = 1.f; double invb = 1.0;
    for (int i = 0; i < h; i++) { iv *= 10.f; invb *= 0.1; }
    const float sf = (float)(6.283185307179586 * invb);
    const float gm = 1.f / (1.f + expf(-gp));
    const float lg = logf(fmaxf(gm, 1e-6f));
    int dstep = its - itp; if (dstep < 0) dstep = 0;
    const float dec = expf(lg * ((float)dstep * sf));
    float p = fmaxf(dec, EPSF);
#pragma unroll
    for (int off = 1; off < 64; off <<= 1) {
        float o = __shfl_up(p, off, 64);
        if (lane >= off) p *= o;
    }
    const float ipv = 1.f / fmaxf(p, EPSF);
    const float tk = fmodf((float)its, iv) * sf;
    const float k0 = cosf(tk), k1 = sinf(tk);
    s_b0[w][lane] = k0 * ipv;
    s_b1[w][lane] = k1 * ipv;
    const float tq = fmodf((float)inx, iv) * sf;
    int dq = inx - its; if (dq < 0) dq = 0;
    const float qd = expf(lg * ((float)dq * sf));
    const float sq = sinf(tq), cq = cosf(tq);
    const int r0i = w * 2, r1i = w * 2 + 1;
    s_a0[r0i][lane] = sq * qd * p * al0;  s_a1[r0i][lane] = -cq * qd * p * al0;
    s_a0[r1i][lane] = cq * qd * p * al1;  s_a1[r1i][lane] = sq * qd * p * al1;
    s_st0[r0i][lane] = st00; s_st1[r0i][lane] = st10;
    s_st0[r1i][lane] = st01; s_st1[r1i][lane] = st11;
    asm volatile("s_waitcnt lgkmcnt(0)" ::: "memory");

    fx4 rb0[2][2], rb1[2][2];
#pragma unroll
    for (int ks = 0; ks < 2; ++ks) {
        const int m0 = ks * 32 + (lane >> 4) * 8;
        rb0[ks][0] = *reinterpret_cast<const fx4*>(&s_b0[w][m0]);
        rb0[ks][1] = *reinterpret_cast<const fx4*>(&s_b0[w][m0 + 4]);
        rb1[ks][0] = *reinterpret_cast<const fx4*>(&s_b1[w][m0]);
        rb1[ks][1] = *reinterpret_cast<const fx4*>(&s_b1[w][m0 + 4]);
    }

#pragma unroll
    for (int cc = 0; cc < 2; ++cc) {
        const int reg = w * 2 + cc;
        const int c = h + cc * 8;
        const char* vbase2 = (const char*)&vt[reg][0];

        bhx8 pa[4][2];
#pragma unroll
        for (int mi = 0; mi < 4; ++mi) {
            const int l = mi * 16 + (lane & 15);
            const float a0l = s_a0[reg][l];
            const float a1l = s_a1[reg][l];
#pragma unroll
            for (int ks = 0; ks < 2; ++ks) {
                if (mi * 16 + 16 <= ks * 32) continue;
                const bool full = (mi * 16 >= ks * 32 + 32);
                bhx8 v;
#pragma unroll
                for (int jj = 0; jj < 8; ++jj) {
                    const int m = ks * 32 + (lane >> 4) * 8 + jj;
                    const float b0m = rb0[ks][jj >> 2][jj & 3];
                    const float b1m = rb1[ks][jj >> 2][jj & 3];
                    const float val = a0l * b0m + a1l * b1m;
                    v[jj] = (full || l >= m) ? (bh)val : (bh)0.f;
                }
                pa[mi][ks] = v;
            }
        }

        if (cc == 0) { asm volatile("s_waitcnt vmcnt(8)" ::: "memory"); }
        else         { asm volatile("s_waitcnt vmcnt(0)" ::: "memory"); }

        const uint32_t tb = LDSA(vbase2) + ((lane >> 4) << 8) + ((lane & 15) << 3);
        bhx8 pb[4][2];
#pragma unroll
        for (int ni = 0; ni < 4; ++ni)
#pragma unroll
            for (int ks = 0; ks < 2; ++ks) {
                const uint32_t a2 = tb + ni * 2048 + ks * 1024;
                u32x2 lo, hi;
                asm volatile("ds_read_b64_tr_b16 %0, %2 offset:0\n\t"
                             "ds_read_b64_tr_b16 %1, %2 offset:128"
                             : "=&v"(lo), "=&v"(hi) : "v"(a2));
                union { u32x2 u[2]; bhx8 f; } u_;
                u_.u[0] = lo; u_.u[1] = hi;
                pb[ni][ks] = u_.f;
            }
        asm volatile("s_waitcnt lgkmcnt(0)" ::: "memory");
        SB();

        fx4 acc[4][4];
#pragma unroll
        for (int mi = 0; mi < 4; ++mi)
#pragma unroll
            for (int ni = 0; ni < 4; ++ni)
#pragma unroll
                for (int r = 0; r < 4; ++r) acc[mi][ni][r] = 0.f;
        __builtin_amdgcn_s_setprio(1);
#pragma unroll
        for (int ks = 0; ks < 2; ++ks)
#pragma unroll
            for (int mi = 0; mi < 4; ++mi) {
                if (mi * 16 + 16 <= ks * 32) continue;
#pragma unroll
                for (int ni = 0; ni < 4; ++ni)
                    acc[mi][ni] = __builtin_amdgcn_mfma_f32_16x16x32_bf16(
                        pa[mi][ks], pb[ni][ks], acc[mi][ni], 0, 0, 0);
            }
        __builtin_amdgcn_s_setprio(0);
        SB();

        float st0e[4], st1e[4];
#pragma unroll
        for (int ni = 0; ni < 4; ++ni) {
            st0e[ni] = s_st0[reg][ni * 16 + (lane & 15)];
            st1e[ni] = s_st1[reg][ni * 16 + (lane & 15)];
        }
        const float bev = (cc == 0) ? be0 : be1;
        float* ob = outp + ((size_t)b * SS + (size_t)j * 64) * DIMD + c * 64 + (lane & 15);
#pragma unroll
        for (int mi = 0; mi < 4; ++mi)
#pragma unroll
            for (int r = 0; r < 4; ++r) {
                const int l = mi * 16 + ((lane >> 4) << 2) + r;
                const float a0l = s_a0[reg][l];
                const float a1l = s_a1[reg][l];
#pragma unroll
                for (int ni = 0; ni < 4; ++ni) {
                    const float vv = (float)*reinterpret_cast<const bh*>(
                        vbase2 + ni * 2048 + (mi * 4 + (lane >> 4)) * 128 + r * 32 + ((lane & 15) << 1));
                    const float o = acc[mi][ni][r] + a0l * st0e[ni] + a1l * st1e[ni] + bev * vv;
                    ob[(size_t)l * DIMD + ni * 16] = o;
                }
            }
    }
}

// ---------------- per-chunk output (f32 fallback, tiers 2/3) ----------------
template <typename VT>
__global__ __launch_bounds__(256) void kc_k(const int* __restrict__ ts,
                                            const int* __restrict__ nts,
                                            const float* __restrict__ gammap,
                                            const float* __restrict__ alphap,
                                            const float* __restrict__ betap,
                                            const VT* values,     // may alias outp
                                            const float* __restrict__ Sws,
                                            float* outp) {
    __shared__ float vsm[64][64];
    __shared__ float s_p[64], s_ip[64], s_k0[64], s_k1[64], s_q0[64], s_q1[64];
    __shared__ float s_st[128];
    int bid = blockIdx.x;
    int j = bid & 127;
    int c = (bid >> 7) & 15;
    int b = bid >> 11;
    int h = c & 7;
    int tid = threadIdx.x;
    if (tid < 64) {
        int l = tid;
        int s = j * 64 + l;
        float iv = 1.f; double invb = 1.0;
        for (int i = 0; i < h; i++) { iv *= 10.f; invb *= 0.1; }
        float sf = (float)(6.283185307179586 * invb);
        float gp = gammap[h];
        float gm = 1.f / (1.f + expf(-gp));
        float lg = logf(fmaxf(gm, 1e-6f));
        int its = ts[b * SS + s];
        int itp = (s > 0) ? ts[b * SS + s - 1] : its;
        int dstep = its - itp; if (dstep < 0) dstep = 0;
        float dec = expf(lg * ((float)dstep * sf));
        float p = fmaxf(dec, EPSF);
#pragma unroll
        for (int off = 1; off < 64; off <<= 1) {
            float o = __shfl_up(p, off, 64);
            if (l >= off) p *= o;
        }
        s_p[l] = p;
        s_ip[l] = 1.f / fmaxf(p, EPSF);
        float tk = fmodf((float)its, iv) * sf;
        s_k0[l] = cosf(tk);
        s_k1[l] = sinf(tk);
        int inx = nts[b * SS + s];
        float tq = fmodf((float)inx, iv) * sf;
        int dq = inx - its; if (dq < 0) dq = 0;
        float qd = expf(lg * ((float)dq * sf));
        float sq = sinf(tq), cq2 = cosf(tq);
        s_q0[l] = (c < 8) ? sq * qd : cq2 * qd;
        s_q1[l] = (c < 8) ? (-cq2 * qd) : sq * qd;
    }
    const VT* vbase = values + ((size_t)b * SS + (size_t)j * 64) * DIMD + c * 64;
#pragma unroll
    for (int i = 0; i < 2; ++i) {
        int f = tid + i * 256;
        int row = f >> 3;
        int c8 = f & 7;
        if constexpr (sizeof(VT) == 2) {
            bhx8 v8 = *reinterpret_cast<const bhx8*>(vbase + (size_t)row * DIMD + c8 * 8);
#pragma unroll
            for (int r = 0; r < 8; ++r) vsm[row][c8 * 8 + r] = (float)v8[r];
        } else {
            *reinterpret_cast<float4*>(&vsm[row][c8 * 8]) =
                *reinterpret_cast<const float4*>(vbase + (size_t)row * DIMD + c8 * 8);
            *reinterpret_cast<float4*>(&vsm[row][c8 * 8 + 4]) =
                *reinterpret_cast<const float4*>(vbase + (size_t)row * DIMD + c8 * 8 + 4);
        }
    }
    if (tid < 128) {
        s_st[tid] = Sws[((size_t)(b * CC + c) * NCH + j) * 128 + tid];
    }
    __syncthreads();
    int l = tid >> 2, eg = tid & 3;
    float acc[16];
#pragma unroll
    for (int i = 0; i < 16; i++) acc[i] = 0.f;
    float q0 = s_q0[l], q1 = s_q1[l], pl_ = s_p[l];
    for (int m = 0; m <= l; ++m) {
        float wgt = (q0 * s_k0[m] + q1 * s_k1[m]) * (pl_ * s_ip[m]);
        const float* vr = &vsm[m][eg * 16];
#pragma unroll
        for (int i = 0; i < 16; i++) acc[i] += wgt * vr[i];
    }
    float al = alphap[c], be = betap[c];
    float* ob = outp + ((size_t)b * SS + (size_t)j * 64 + l) * DIMD + c * 64 + eg * 16;
    const float* st0 = &s_st[eg * 16];
    const float* st1 = &s_st[64 + eg * 16];
#pragma unroll
    for (int i2 = 0; i2 < 4; i2++) {
        float4 vv = *reinterpret_cast<const float4*>(&vsm[l][eg * 16 + i2 * 4]);
        float4 o4;
        const float* vvp = (const float*)&vv;
        float* o4p = (float*)&o4;
#pragma unroll
        for (int r = 0; r < 4; r++) {
            int i = i2 * 4 + r;
            float prevt = pl_ * (q0 * st0[i] + q1 * st1[i]);
            o4p[r] = (prevt + acc[i]) * al + vvp[r] * be;
        }
        *reinterpret_cast<float4*>(ob + i2 * 4) = o4;
    }
}

extern "C" void kernel_launch(void* const* d_in, const int* in_sizes, int n_in,
                              void* d_out, int out_size, void* d_ws, size_t ws_size,
                              hipStream_t stream) {
    const float* inputs = (const float*)d_in[0];
    const float* Wv     = (const float*)d_in[1];
    const float* gammap = (const float*)d_in[2];
    const float* alphap = (const float*)d_in[3];
    const float* betap  = (const float*)d_in[4];
    const int*   ts     = (const int*)d_in[5];
    const int*   nts    = (const int*)d_in[6];
    float* outp = (float*)d_out;
    char* ws = (char*)d_ws;

    float* Aws     = (float*)ws;                    // 4 MiB
    float* plastWs = (float*)(ws + 4194304);        // 32 KiB
    float* Sws     = (float*)(ws + 4227072);        // 4 MiB
    const size_t base   = 8421376;
    const size_t abytes = 67108864;                 // Abf 64 MiB
    const size_t wbytes = 2097152;                  // Wbf 2 MiB
    const size_t vbytes = 67108864;                 // Vbf 64 MiB

    if (ws_size >= base + abytes + wbytes + vbytes) {
        // tier 1: bf16 A/W + bf16 values; ka fused into gemm epilogue
        bh* Abf = (bh*)(ws + base);
        bh* Wbf = (bh*)(ws + base + abytes);
        bh* Vbf = (bh*)(ws + base + abytes + wbytes);
        cvt2_k<<<16896, 256, 0, stream>>>(inputs, Wv, Abf, Wbf);
        gemm256a<bh><<<512, 512, 0, stream>>>(Abf, Wbf, Vbf, ts, gammap, Aws, plastWs);
        kb_k<<<64, 128, 0, stream>>>(Aws, plastWs, Sws);
        kc2_k<<<1024, 256, 0, stream>>>(ts, nts, gammap, alphap, betap, Vbf, Sws, outp);
    } else if (ws_size >= base + abytes + wbytes) {
        // tier 2: bf16 A/W in workspace, f32 values staged in d_out; ka fused
        bh* Abf = (bh*)(ws + base);
        bh* Wbf = (bh*)(ws + base + abytes);
        cvt2_k<<<16896, 256, 0, stream>>>(inputs, Wv, Abf, Wbf);
        gemm256a<float><<<512, 512, 0, stream>>>(Abf, Wbf, outp, ts, gammap, Aws, plastWs);
        kb_k<<<64, 128, 0, stream>>>(Aws, plastWs, Sws);
        kc_k<float><<<8192, 256, 0, stream>>>(ts, nts, gammap, alphap, betap, outp, Sws, outp);
    } else {
        // tier 3: legacy path
        gemm_k<<<2048, 256, 0, stream>>>(inputs, Wv, outp);
        ka_k<float><<<4096, 64, 0, stream>>>(ts, gammap, outp, Aws, plastWs);
        kb_k<<<64, 128, 0, stream>>>(Aws, plastWs, Sws);
        kc_k<float><<<8192, 256, 0, stream>>>(ts, nts, gammap, alphap, betap, outp, Sws, outp);
    }
}

// Round 10
// 168.293 us; speedup vs baseline: 1.3143x; 1.0114x over previous
//
#include <hip/hip_runtime.h>
#include <stdint.h>

#define SS   8192
#define DIMD 1024
#define NCH  128
#define CC   16
#define EPSF 1e-8f

typedef __bf16 bh;
typedef bh    bhx4 __attribute__((ext_vector_type(4)));
typedef bh    bhx8 __attribute__((ext_vector_type(8)));
typedef float fx4  __attribute__((ext_vector_type(4)));
typedef unsigned int u32x2 __attribute__((ext_vector_type(2)));

#define GLOAD_LDS16(g, l) __builtin_amdgcn_global_load_lds(                    \
    (const __attribute__((address_space(1))) uint32_t*)(g),                    \
    (__attribute__((address_space(3))) uint32_t*)(l), 16, 0, 0)

#define LDSA(p) ((uint32_t)(uintptr_t)(const __attribute__((address_space(3))) char*)(const char*)(p))

#define SB() __builtin_amdgcn_sched_barrier(0)
#define PRE_BAR()  do { SB(); __builtin_amdgcn_s_barrier(); SB();              \
                        __builtin_amdgcn_s_setprio(1); } while (0)
#define POST_BAR() do { __builtin_amdgcn_s_setprio(0); SB();                   \
                        __builtin_amdgcn_s_barrier(); SB(); } while (0)

// ---------------- merged f32 -> bf16 convert (Wv + inputs, one launch) ------
__global__ __launch_bounds__(256) void cvt2_k(const float* __restrict__ srcA,
                                              const float* __restrict__ srcW,
                                              bh* __restrict__ dstA,
                                              bh* __restrict__ dstW) {
    const int i = blockIdx.x * 256 + threadIdx.x;
    const float* src;
    bh* dst;
    int idx;
    if (i < 131072) { src = srcW; dst = dstW; idx = i; }
    else            { src = srcA; dst = dstA; idx = i - 131072; }
    const float4 a = reinterpret_cast<const float4*>(src)[idx * 2];
    const float4 b = reinterpret_cast<const float4*>(src)[idx * 2 + 1];
    bhx8 o;
    o[0] = (bh)a.x; o[1] = (bh)a.y; o[2] = (bh)a.z; o[3] = (bh)a.w;
    o[4] = (bh)b.x; o[5] = (bh)b.y; o[6] = (bh)b.z; o[7] = (bh)b.w;
    reinterpret_cast<bhx8*>(dst)[idx] = o;
}

// ---------------- bf16 GEMM + fused ka: C = A @ Bw^T, A_j, plast_j ----------
// (exact Round-5/9 best-measured version — DO NOT TOUCH)
template <typename VT>
__global__ __launch_bounds__(512, 2) void gemm256a(const bh* __restrict__ A,
                                                   const bh* __restrict__ Bw,
                                                   VT* __restrict__ C,
                                                   const int* __restrict__ tsp,
                                                   const float* __restrict__ gammap,
                                                   float* __restrict__ Aws,
                                                   float* __restrict__ plastWs) {
    __shared__ __align__(16) char ldsraw[131072];
    const int lb = blockIdx.x;
    const int logical = (lb & 7) * 64 + (lb >> 3);   // XCD-chunked, bijective (512 wg)
    const int mt = logical >> 2;                     // 128 m-tiles
    const int nt = logical & 3;                      // 4 n-tiles
    const int tid = threadIdx.x, lane = tid & 63, w = tid >> 6;
    const int wm = w >> 2, wn = w & 3;

    fx4 acc[8][4];
#pragma unroll
    for (int i = 0; i < 8; ++i)
#pragma unroll
        for (int j = 0; j < 4; ++j)
#pragma unroll
            for (int r = 0; r < 4; ++r) acc[i][j][r] = 0.f;

    const int kgo = ((tid & 3) ^ ((tid >> 3) & 3)) << 3;   // element offset
    const bh* gA0 = A  + (size_t)(mt * 256 + (tid >> 2)) * DIMD + kgo;
    const bh* gB0 = Bw + (size_t)(nt * 256 + (tid >> 2)) * DIMD + kgo;

#define STAGE_U(kt, obase, g, h)                                               \
    { char* lp = ldsraw + ((((kt) & 1) * 65536) + (obase) + (h) * 16384) + tid * 16; \
      const bh* gp = (g) + (kt) * 64 + (h) * 32;                               \
      GLOAD_LDS16(gp, lp);                                                     \
      GLOAD_LDS16(gp + 131072, lp + 8192); }

    const int rAb = wm * 128 + (lane & 15);
    const int rBb = wn * 64 + (lane & 15);
    const int s_swz = (lane >> 4) ^ (((lane & 15) >> 1) & 3);
    const int offA = rAb * 64 + s_swz * 16;
    const int offB = rBb * 64 + s_swz * 16;

    STAGE_U(0, 0, gA0, 0); STAGE_U(0, 32768, gB0, 0);
    STAGE_U(0, 0, gA0, 1); STAGE_U(0, 32768, gB0, 1);
    STAGE_U(1, 0, gA0, 0); STAGE_U(1, 32768, gB0, 0);
    STAGE_U(1, 0, gA0, 1); STAGE_U(1, 32768, gB0, 1);
    asm volatile("s_waitcnt vmcnt(8)" ::: "memory");   // tile0 landed
    SB(); __builtin_amdgcn_s_barrier(); SB();

#pragma unroll 2
    for (int t = 0; t < 16; ++t) {
        const int buf = t & 1;
        const char* pA0 = ldsraw + buf * 65536 + offA;            // A kh0
        const char* pB0 = ldsraw + buf * 65536 + 32768 + offB;    // B kh0
        bhx8 fa[4], fb[4];

        // ---- G1: (mq0, k0) ----
#pragma unroll
        for (int i = 0; i < 4; ++i) fa[i] = *reinterpret_cast<const bhx8*>(pA0 + i * 1024);
#pragma unroll
        for (int j = 0; j < 4; ++j) fb[j] = *reinterpret_cast<const bhx8*>(pB0 + j * 1024);
        if (t >= 1 && t <= 14) STAGE_U(t + 1, 0, gA0, 1);
        PRE_BAR();
#pragma unroll
        for (int i = 0; i < 4; ++i)
#pragma unroll
            for (int j = 0; j < 4; ++j)
                acc[i][j] = __builtin_amdgcn_mfma_f32_16x16x32_bf16(fa[i], fb[j], acc[i][j], 0, 0, 0);
        POST_BAR();

        // ---- G2: (mq1, k0) ----
#pragma unroll
        for (int i = 0; i < 4; ++i) fa[i] = *reinterpret_cast<const bhx8*>(pA0 + (4 + i) * 1024);
        if (t <= 13) STAGE_U(t + 2, 32768, gB0, 0);
        PRE_BAR();
#pragma unroll
        for (int i = 0; i < 4; ++i)
#pragma unroll
            for (int j = 0; j < 4; ++j)
                acc[4 + i][j] = __builtin_amdgcn_mfma_f32_16x16x32_bf16(fa[i], fb[j], acc[4 + i][j], 0, 0, 0);
        POST_BAR();

        // ---- G3: (mq0, k1) ----
#pragma unroll
        for (int i = 0; i < 4; ++i) fa[i] = *reinterpret_cast<const bhx8*>(pA0 + 16384 + i * 1024);
#pragma unroll
        for (int j = 0; j < 4; ++j) fb[j] = *reinterpret_cast<const bhx8*>(pB0 + 16384 + j * 1024);
        if (t <= 13) STAGE_U(t + 2, 0, gA0, 0);
        PRE_BAR();
#pragma unroll
        for (int i = 0; i < 4; ++i)
#pragma unroll
            for (int j = 0; j < 4; ++j)
                acc[i][j] = __builtin_amdgcn_mfma_f32_16x16x32_bf16(fa[i], fb[j], acc[i][j], 0, 0, 0);
        POST_BAR();

        // ---- G4: (mq1, k1) ----
#pragma unroll
        for (int i = 0; i < 4; ++i) fa[i] = *reinterpret_cast<const bhx8*>(pA0 + 16384 + (4 + i) * 1024);
        if (t <= 13) STAGE_U(t + 2, 32768, gB0, 1);
        PRE_BAR();
#pragma unroll
        for (int i = 0; i < 4; ++i)
#pragma unroll
            for (int j = 0; j < 4; ++j)
                acc[4 + i][j] = __builtin_amdgcn_mfma_f32_16x16x32_bf16(fa[i], fb[j], acc[4 + i][j], 0, 0, 0);
        __builtin_amdgcn_s_setprio(0);
        if (t < 14)       { asm volatile("s_waitcnt vmcnt(6)" ::: "memory"); }
        else if (t == 14) { asm volatile("s_waitcnt vmcnt(0)" ::: "memory"); }
        SB(); __builtin_amdgcn_s_barrier(); SB();
    }
#undef STAGE_U

    // ---- C-store: col = lane&15, row = (lane>>4)*4 + r (m89-verified) ----
    const int r0 = (lane >> 4) * 4;
    const int c0 = lane & 15;
#pragma unroll
    for (int mi = 0; mi < 8; ++mi) {
#pragma unroll
        for (int ni = 0; ni < 4; ++ni) {
            const size_t m = (size_t)(mt * 256 + wm * 128 + mi * 16 + r0);
            const int    n = nt * 256 + wn * 64 + ni * 16 + c0;
#pragma unroll
            for (int r = 0; r < 4; ++r) {
                if constexpr (sizeof(VT) == 2)
                    C[(m + r) * DIMD + n] = (bh)acc[mi][ni][r];
                else
                    C[(m + r) * DIMD + n] = acc[mi][ni][r];
            }
        }
    }

    // ================= fused ka epilogue =================
    float* wlds = (float*)ldsraw + w * 256;
    const int b_ = mt >> 5;
    const int j0 = (mt & 31) * 4;
    const int c_ = nt * 4 + wn;
    const int h_ = c_ & 7;
    float iv = 1.f; double invb = 1.0;
    for (int i = 0; i < h_; i++) { iv *= 10.f; invb *= 0.1; }
    const float sf = (float)(6.283185307179586 * invb);
    const float gm = 1.f / (1.f + expf(-gammap[h_]));
    const float lg = logf(fmaxf(gm, 1e-6f));

#pragma unroll
    for (int jl = 0; jl < 2; ++jl) {
        const int jg = j0 + wm * 2 + jl;
        const int sl = jg * 64 + lane;                 // batch-local index
        const int its = tsp[b_ * SS + sl];
        const int itp = (sl > 0) ? tsp[b_ * SS + sl - 1] : its;
        int dstep = its - itp; if (dstep < 0) dstep = 0;
        const float dec = expf(lg * ((float)dstep * sf));
        float p = fmaxf(dec, EPSF);
#pragma unroll
        for (int off = 1; off < 64; off <<= 1) {
            float o = __shfl_up(p, off, 64);
            if (lane >= off) p *= o;
        }
        const float plast = __shfl(p, 63, 64);
        const float swv = plast / fmaxf(p, EPSF);
        const float tk = fmodf((float)its, iv) * sf;
        wlds[jl * 128 + lane]      = cosf(tk) * swv;
        wlds[jl * 128 + 64 + lane] = sinf(tk) * swv;
        if (lane == 0) plastWs[(size_t)(b_ * CC + c_) * NCH + jg] = plast;
    }
    asm volatile("s_waitcnt lgkmcnt(0)" ::: "memory");

#pragma unroll
    for (int jl = 0; jl < 2; ++jl) {
        const int jg = j0 + wm * 2 + jl;
        float* ab = Aws + ((size_t)(b_ * CC + c_) * NCH + jg) * 128;
        fx4 w0q[4], w1q[4];
        const int gb = ((lane >> 4) << 2);
#pragma unroll
        for (int q = 0; q < 4; ++q) {
            w0q[q] = *reinterpret_cast<const fx4*>(&wlds[jl * 128 + q * 16 + gb]);
            w1q[q] = *reinterpret_cast<const fx4*>(&wlds[jl * 128 + 64 + q * 16 + gb]);
        }
#pragma unroll
        for (int ni = 0; ni < 4; ++ni) {
            float pa0 = 0.f, pa1 = 0.f;
#pragma unroll
            for (int q = 0; q < 4; ++q)
#pragma unroll
                for (int r = 0; r < 4; ++r) {
                    const float av = acc[jl * 4 + q][ni][r];
                    pa0 += w0q[q][r] * av;
                    pa1 += w1q[q][r] * av;
                }
            pa0 += __shfl_xor(pa0, 16, 64); pa0 += __shfl_xor(pa0, 32, 64);
            pa1 += __shfl_xor(pa1, 16, 64); pa1 += __shfl_xor(pa1, 32, 64);
            const int e = ni * 16 + (lane & 15);
            const int grp = lane >> 4;
            if (grp == 0)      ab[e] = pa0;
            else if (grp == 1) ab[64 + e] = pa1;
        }
    }
}

// ---------------- legacy f32 GEMM (tier-3 fallback) -------------------------
__global__ __launch_bounds__(256) void gemm_k(const float* __restrict__ Ain,
                                              const float* __restrict__ Win,
                                              float* __restrict__ Cout) {
    __shared__ __align__(16) char ldsraw[20480];
    char* ldsA = ldsraw;
    char* ldsB = ldsraw + 10240;
    const int tid = threadIdx.x;
    const int lane = tid & 63;
    const int w = tid >> 6;
    const int wm = w >> 1, wn = w & 1;
    const int bid = blockIdx.x;
    const int mt = bid >> 3;
    const int nt = bid & 7;
    const size_t Abase = (size_t)mt * 128 * 1024;
    const size_t Bbase = (size_t)nt * 128 * 1024;
    fx4 acc[4][4];
#pragma unroll
    for (int i = 0; i < 4; i++)
#pragma unroll
        for (int j2 = 0; j2 < 4; j2++)
#pragma unroll
            for (int r = 0; r < 4; r++) acc[i][j2][r] = 0.f;
    const int srow0 = tid >> 3;
    const int sc16 = tid & 7;
    for (int kt = 0; kt < 32; ++kt) {
        const int k0 = kt * 32;
#pragma unroll
        for (int jj = 0; jj < 4; jj++) {
            int row = srow0 + jj * 32;
            const float4 va = *reinterpret_cast<const float4*>(Ain + Abase + (size_t)row * 1024 + k0 + sc16 * 4);
            const float4 vb = *reinterpret_cast<const float4*>(Win + Bbase + (size_t)row * 1024 + k0 + sc16 * 4);
            bhx4 ba, bb2;
            ba[0] = (bh)va.x; ba[1] = (bh)va.y; ba[2] = (bh)va.z; ba[3] = (bh)va.w;
            bb2[0] = (bh)vb.x; bb2[1] = (bh)vb.y; bb2[2] = (bh)vb.z; bb2[3] = (bh)vb.w;
            *reinterpret_cast<bhx4*>(ldsA + row * 80 + sc16 * 8) = ba;
            *reinterpret_cast<bhx4*>(ldsB + row * 80 + sc16 * 8) = bb2;
        }
        __syncthreads();
        bhx8 fa[4], fb[4];
        const int kb = (lane >> 4) * 16;
        const int rA = wm * 64 + (lane & 15);
        const int rB = wn * 64 + (lane & 15);
#pragma unroll
        for (int mi = 0; mi < 4; mi++) fa[mi] = *reinterpret_cast<const bhx8*>(ldsA + (rA + mi * 16) * 80 + kb);
#pragma unroll
        for (int ni = 0; ni < 4; ni++) fb[ni] = *reinterpret_cast<const bhx8*>(ldsB + (rB + ni * 16) * 80 + kb);
#pragma unroll
        for (int mi = 0; mi < 4; mi++)
#pragma unroll
            for (int ni = 0; ni < 4; ni++)
                acc[mi][ni] = __builtin_amdgcn_mfma_f32_16x16x32_bf16(fa[mi], fb[ni], acc[mi][ni], 0, 0, 0);
        __syncthreads();
    }
    const int r0 = (lane >> 4) * 4;
    const int cc0 = lane & 15;
#pragma unroll
    for (int mi = 0; mi < 4; mi++) {
#pragma unroll
        for (int ni = 0; ni < 4; ni++) {
            size_t rr = (size_t)(mt * 128 + wm * 64 + mi * 16 + r0);
            int cc = nt * 128 + wn * 64 + ni * 16 + cc0;
#pragma unroll
            for (int r = 0; r < 4; r++) Cout[(rr + r) * 1024 + cc] = acc[mi][ni][r];
        }
    }
}

// ---------------- per-chunk A_j and plast_j (tier-3 only) -------------------
template <typename VT>
__global__ __launch_bounds__(64) void ka_k(const int* __restrict__ ts,
                                           const float* __restrict__ gammap,
                                           const VT* values,
                                           float* __restrict__ Aws,
                                           float* __restrict__ plastWs) {
    __shared__ float s_k0[64], s_k1[64];
    int bid = blockIdx.x;
    int j = bid & 127;
    int h = (bid >> 7) & 7;
    int b = bid >> 10;
    int l = threadIdx.x;
    int s = j * 64 + l;
    float iv = 1.f; double invb = 1.0;
    for (int i = 0; i < h; i++) { iv *= 10.f; invb *= 0.1; }
    float sf = (float)(6.283185307179586 * invb);
    float gp = gammap[h];
    float gm = 1.f / (1.f + expf(-gp));
    float lg = logf(fmaxf(gm, 1e-6f));
    int its = ts[b * SS + s];
    int itp = (s > 0) ? ts[b * SS + s - 1] : its;
    int dstep = its - itp; if (dstep < 0) dstep = 0;
    float dec = expf(lg * ((float)dstep * sf));
    float p = fmaxf(dec, EPSF);
#pragma unroll
    for (int off = 1; off < 64; off <<= 1) {
        float o = __shfl_up(p, off, 64);
        if (l >= off) p *= o;
    }
    float plast = __shfl(p, 63, 64);
    float swv = plast / fmaxf(p, EPSF);
    float tk = fmodf((float)its, iv) * sf;
    s_k0[l] = cosf(tk) * swv;
    s_k1[l] = sinf(tk) * swv;
    __syncthreads();
    if (l == 0) {
        plastWs[(b * CC + h) * NCH + j] = plast;
        plastWs[(b * CC + h + 8) * NCH + j] = plast;
    }
    int e = l;
#pragma unroll
    for (int cc2 = 0; cc2 < 2; ++cc2) {
        int c = h + cc2 * 8;
        const VT* vb = values + ((size_t)b * SS + (size_t)j * 64) * DIMD + c * 64 + e;
        float a0 = 0.f, a1 = 0.f;
#pragma unroll 8
        for (int m = 0; m < 64; ++m) {
            float vv = (float)vb[(size_t)m * DIMD];
            a0 += s_k0[m] * vv;
            a1 += s_k1[m] * vv;
        }
        float* ab = Aws + ((size_t)(b * CC + c) * NCH + j) * 128;
        ab[e] = a0;
        ab[64 + e] = a1;
    }
}

// ---------------- inter-chunk linear scan (LDS bulk-staged) -----------------
__global__ __launch_bounds__(128) void kb_k(const float* __restrict__ Aws,
                                            const float* __restrict__ plastWs,
                                            float* __restrict__ Sws) {
    __shared__ float pl[NCH];
    __shared__ __align__(16) float sa[NCH][128];       // 64 KiB
    const int bc = blockIdx.x;
    const int t = threadIdx.x;
    const int wv = t >> 6;          // wave id (uniform per wave)
    const int ln = t & 63;
    pl[t] = plastWs[bc * NCH + t];
    const float* ab = Aws + (size_t)bc * NCH * 128;
#pragma unroll
    for (int i = 0; i < 32; ++i) {
        const int row = i * 4 + wv * 2;
        GLOAD_LDS16(ab + (size_t)row * 128 + ln * 4, (char*)&sa[row][0] + ln * 16);
    }
    asm volatile("s_waitcnt vmcnt(0)" ::: "memory");
    __syncthreads();
    float st = 0.f;
    float* sb = Sws + (size_t)bc * NCH * 128 + t;
#pragma unroll 4
    for (int j = 0; j < NCH; ++j) {
        sb[(size_t)j * 128] = st;
        st = st * pl[j] + sa[j][t];
    }
}

// ---------------- per-chunk output, MFMA version (tier-1, bf16 V) -----------
// beta*V via identity A-fragments (R6-validated); state term folded into acc
// in registers; output stored via LDS-transposed float4 path (vt[w*2] reused
// as 8 KiB scratch, rotation swizzle slot' = (slot+row)&15 -> 2-way max).
__global__ __launch_bounds__(256, 2) void kc2_k(const int* __restrict__ ts,
                                                const int* __restrict__ nts,
                                                const float* __restrict__ gammap,
                                                const float* __restrict__ alphap,
                                                const float* __restrict__ betap,
                                                const bh* __restrict__ values,
                                                const float* __restrict__ Sws,
                                                float* __restrict__ outp) {
    __shared__ __align__(16) bh vt[8][4096];       // 8 regions x 8 KiB
    __shared__ float s_b0[4][64], s_b1[4][64];     // per-h (wave)
    __shared__ float s_a0[8][64], s_a1[8][64];     // per region (w,cc)
    __shared__ float s_st0[8][64], s_st1[8][64];   // per region

    const int bid = blockIdx.x;
    const int g = bid & 1;
    const int j = (bid >> 1) & 127;
    const int b = bid >> 8;
    const int tid = threadIdx.x, lane = tid & 63, w = tid >> 6;
    const int h = g * 4 + w;
    const int s = j * 64 + lane;

    const int its = ts[b * SS + s];
    const int itp = (s > 0) ? ts[b * SS + s - 1] : its;
    const int inx = nts[b * SS + s];
    const float* swp0 = Sws + ((size_t)(b * CC + h) * NCH + j) * 128;
    const float* swp1 = Sws + ((size_t)(b * CC + h + 8) * NCH + j) * 128;
    const float st00 = swp0[lane], st10 = swp0[64 + lane];
    const float st01 = swp1[lane], st11 = swp1[64 + lane];
    const float al0 = alphap[h], al1 = alphap[h + 8];
    const float be0 = betap[h], be1 = betap[h + 8];
    const float gp = gammap[h];

    const bh* gv0 = values + ((size_t)b * SS + (size_t)j * 64 + (lane >> 1)) * DIMD
                    + h * 64 + (lane & 1) * 8;
    const bh* gv1 = gv0 + 512;                     // channel h+8
    char* lc0 = (char*)&vt[w * 2][0] + lane * 16;
    char* lc1 = (char*)&vt[w * 2 + 1][0] + lane * 16;
#pragma unroll
    for (int mh = 0; mh < 2; ++mh)
#pragma unroll
        for (int pp = 0; pp < 4; ++pp)
            GLOAD_LDS16(gv0 + mh * 32 * DIMD + pp * 16, lc0 + pp * 2048 + mh * 1024);
#pragma unroll
    for (int mh = 0; mh < 2; ++mh)
#pragma unroll
        for (int pp = 0; pp < 4; ++pp)
            GLOAD_LDS16(gv1 + mh * 32 * DIMD + pp * 16, lc1 + pp * 2048 + mh * 1024);

    float iv = 1.f; double invb = 1.0;
    for (int i = 0; i < h; i++) { iv *= 10.f; invb *= 0.1; }
    const float sf = (float)(6.283185307179586 * invb);
    const float gm = 1.f / (1.f + expf(-gp));
    const float lg = logf(fmaxf(gm, 1e-6f));
    int dstep = its - itp; if (dstep < 0) dstep = 0;
    const float dec = expf(lg * ((float)dstep * sf));
    float p = fmaxf(dec, EPSF);
#pragma unroll
    for (int off = 1; off < 64; off <<= 1) {
        float o = __shfl_up(p, off, 64);
        if (lane >= off) p *= o;
    }
    const float ipv = 1.f / fmaxf(p, EPSF);
    const float tk = fmodf((float)its, iv) * sf;
    const float k0 = cosf(tk), k1 = sinf(tk);
    s_b0[w][lane] = k0 * ipv;
    s_b1[w][lane] = k1 * ipv;
    const float tq = fmodf((float)inx, iv) * sf;
    int dq = inx - its; if (dq < 0) dq = 0;
    const float qd = expf(lg * ((float)dq * sf));
    const float sq = sinf(tq), cq = cosf(tq);
    const int r0i = w * 2, r1i = w * 2 + 1;
    s_a0[r0i][lane] = sq * qd * p * al0;  s_a1[r0i][lane] = -cq * qd * p * al0;
    s_a0[r1i][lane] = cq * qd * p * al1;  s_a1[r1i][lane] = sq * qd * p * al1;
    s_st0[r0i][lane] = st00; s_st1[r0i][lane] = st10;
    s_st0[r1i][lane] = st01; s_st1[r1i][lane] = st11;
    asm volatile("s_waitcnt lgkmcnt(0)" ::: "memory");

    fx4 rb0[2][2], rb1[2][2];
#pragma unroll
    for (int ks = 0; ks < 2; ++ks) {
        const int m0 = ks * 32 + (lane >> 4) * 8;
        rb0[ks][0] = *reinterpret_cast<const fx4*>(&s_b0[w][m0]);
        rb0[ks][1] = *reinterpret_cast<const fx4*>(&s_b0[w][m0 + 4]);
        rb1[ks][0] = *reinterpret_cast<const fx4*>(&s_b1[w][m0]);
        rb1[ks][1] = *reinterpret_cast<const fx4*>(&s_b1[w][m0 + 4]);
    }

    char* scr = (char*)&vt[w * 2][0];              // 8 KiB wave-private scratch
    const size_t bSSj = (size_t)b * SS + (size_t)j * 64;

#pragma unroll
    for (int cc = 0; cc < 2; ++cc) {
        const int reg = w * 2 + cc;
        const int c = h + cc * 8;
        const char* vbase2 = (const char*)&vt[reg][0];
        const float bev = (cc == 0) ? be0 : be1;

        bhx8 pa[4][2];
#pragma unroll
        for (int mi = 0; mi < 4; ++mi) {
            const int l = mi * 16 + (lane & 15);
            const float a0l = s_a0[reg][l];
            const float a1l = s_a1[reg][l];
#pragma unroll
            for (int ks = 0; ks < 2; ++ks) {
                if (mi * 16 + 16 <= ks * 32) continue;
                const bool full = (mi * 16 >= ks * 32 + 32);
                bhx8 v;
#pragma unroll
                for (int jj = 0; jj < 8; ++jj) {
                    const int m = ks * 32 + (lane >> 4) * 8 + jj;
                    const float b0m = rb0[ks][jj >> 2][jj & 3];
                    const float b1m = rb1[ks][jj >> 2][jj & 3];
                    const float val = a0l * b0m + a1l * b1m;
                    v[jj] = (full || l >= m) ? (bh)val : (bh)0.f;
                }
                pa[mi][ks] = v;
            }
        }

        // identity A-fragments for beta*V: A[l][k]=bev iff k==(mi&1)*16+l
        bhx8 idf[2];
#pragma unroll
        for (int me = 0; me < 2; ++me) {
            bhx8 z;
#pragma unroll
            for (int jj = 0; jj < 8; ++jj) z[jj] = (bh)0.f;
            const int jj = (lane & 15) + me * 16 - (lane >> 4) * 8;
            if (jj >= 0 && jj < 8) z[jj] = (bh)bev;
            idf[me] = z;
        }

        if (cc == 0) { asm volatile("s_waitcnt vmcnt(8)" ::: "memory"); }
        else         { asm volatile("s_waitcnt vmcnt(0)" ::: "memory"); }

        const uint32_t tb = LDSA(vbase2) + ((lane >> 4) << 8) + ((lane & 15) << 3);
        bhx8 pb[4][2];
#pragma unroll
        for (int ni = 0; ni < 4; ++ni)
#pragma unroll
            for (int ks = 0; ks < 2; ++ks) {
                const uint32_t a2 = tb + ni * 2048 + ks * 1024;
                u32x2 lo, hi;
                asm volatile("ds_read_b64_tr_b16 %0, %2 offset:0\n\t"
                             "ds_read_b64_tr_b16 %1, %2 offset:128"
                             : "=&v"(lo), "=&v"(hi) : "v"(a2));
                union { u32x2 u[2]; bhx8 f; } u_;
                u_.u[0] = lo; u_.u[1] = hi;
                pb[ni][ks] = u_.f;
            }
        asm volatile("s_waitcnt lgkmcnt(0)" ::: "memory");
        SB();

        fx4 acc[4][4];
#pragma unroll
        for (int mi = 0; mi < 4; ++mi)
#pragma unroll
            for (int ni = 0; ni < 4; ++ni)
#pragma unroll
                for (int r = 0; r < 4; ++r) acc[mi][ni][r] = 0.f;
        __builtin_amdgcn_s_setprio(1);
#pragma unroll
        for (int ks = 0; ks < 2; ++ks)
#pragma unroll
            for (int mi = 0; mi < 4; ++mi) {
                if (mi * 16 + 16 <= ks * 32) continue;
#pragma unroll
                for (int ni = 0; ni < 4; ++ni)
                    acc[mi][ni] = __builtin_amdgcn_mfma_f32_16x16x32_bf16(
                        pa[mi][ks], pb[ni][ks], acc[mi][ni], 0, 0, 0);
            }
        // beta*V via identity fragments (diag blocks: ks = mi>>1)
#pragma unroll
        for (int mi = 0; mi < 4; ++mi) {
            const int ks = mi >> 1;
#pragma unroll
            for (int ni = 0; ni < 4; ++ni)
                acc[mi][ni] = __builtin_amdgcn_mfma_f32_16x16x32_bf16(
                    idf[mi & 1], pb[ni][ks], acc[mi][ni], 0, 0, 0);
        }
        __builtin_amdgcn_s_setprio(0);
        SB();

        // ---- fold state term into acc (registers) ----
        float st0e[4], st1e[4];
#pragma unroll
        for (int ni = 0; ni < 4; ++ni) {
            st0e[ni] = s_st0[reg][ni * 16 + (lane & 15)];
            st1e[ni] = s_st1[reg][ni * 16 + (lane & 15)];
        }
#pragma unroll
        for (int mi = 0; mi < 4; ++mi)
#pragma unroll
            for (int r = 0; r < 4; ++r) {
                const int l = mi * 16 + ((lane >> 4) << 2) + r;
                const float a0l = s_a0[reg][l];
                const float a1l = s_a1[reg][l];
#pragma unroll
                for (int ni = 0; ni < 4; ++ni)
                    acc[mi][ni][r] += a0l * st0e[ni] + a1l * st1e[ni];
            }

        // ---- transposed vectorized store via scratch ----
        // scratch logical [32 rows][16 slots of 16B]; phys slot' = (slot+row)&15
#pragma unroll
        for (int mh = 0; mh < 2; ++mh) {
#pragma unroll
            for (int mq = 0; mq < 2; ++mq) {
                const int mi = mh * 2 + mq;
                const int rlb = mq * 16 + ((lane >> 4) << 2);
#pragma unroll
                for (int ni = 0; ni < 4; ++ni) {
                    const int slot = ni * 4 + ((lane & 15) >> 2);
#pragma unroll
                    for (int r = 0; r < 4; ++r) {
                        const int rl = rlb + r;
                        const int sp = (slot + rl) & 15;
                        *(float*)(scr + rl * 256 + sp * 16 + (lane & 3) * 4) = acc[mi][ni][r];
                    }
                }
            }
            asm volatile("s_waitcnt lgkmcnt(0)" ::: "memory");
            SB();
#pragma unroll
            for (int i = 0; i < 8; ++i) {
                const int rr = (lane >> 4) + i * 4;
                const int sp = ((lane & 15) + rr) & 15;
                const fx4 v4 = *reinterpret_cast<const fx4*>(scr + rr * 256 + sp * 16);
                float* op = outp + (bSSj + mh * 32 + rr) * DIMD + c * 64 + (lane & 15) * 4;
                *reinterpret_cast<fx4*>(op) = v4;
            }
            asm volatile("s_waitcnt lgkmcnt(0)" ::: "memory");
            SB();
        }
    }
}

// ---------------- per-chunk output (f32 fallback, tiers 2/3) ----------------
template <typename VT>
__global__ __launch_bounds__(256) void kc_k(const int* __restrict__ ts,
                                            const int* __restrict__ nts,
                                            const float* __restrict__ gammap,
                                            const float* __restrict__ alphap,
                                            const float* __restrict__ betap,
                                            const VT* values,     // may alias outp
                                            const float* __restrict__ Sws,
                                            float* outp) {
    __shared__ float vsm[64][64];
    __shared__ float s_p[64], s_ip[64], s_k0[64], s_k1[64], s_q0[64], s_q1[64];
    __shared__ float s_st[128];
    int bid = blockIdx.x;
    int j = bid & 127;
    int c = (bid >> 7) & 15;
    int b = bid >> 11;
    int h = c & 7;
    int tid = threadIdx.x;
    if (tid < 64) {
        int l = tid;
        int s = j * 64 + l;
        float iv = 1.f; double invb = 1.0;
        for (int i = 0; i < h; i++) { iv *= 10.f; invb *= 0.1; }
        float sf = (float)(6.283185307179586 * invb);
        float gp = gammap[h];
        float gm = 1.f / (1.f + expf(-gp));
        float lg = logf(fmaxf(gm, 1e-6f));
        int its = ts[b * SS + s];
        int itp = (s > 0) ? ts[b * SS + s - 1] : its;
        int dstep = its - itp; if (dstep < 0) dstep = 0;
        float dec = expf(lg * ((float)dstep * sf));
        float p = fmaxf(dec, EPSF);
#pragma unroll
        for (int off = 1; off < 64; off <<= 1) {
            float o = __shfl_up(p, off, 64);
            if (l >= off) p *= o;
        }
        s_p[l] = p;
        s_ip[l] = 1.f / fmaxf(p, EPSF);
        float tk = fmodf((float)its, iv) * sf;
        s_k0[l] = cosf(tk);
        s_k1[l] = sinf(tk);
        int inx = nts[b * SS + s];
        float tq = fmodf((float)inx, iv) * sf;
        int dq = inx - its; if (dq < 0) dq = 0;
        float qd = expf(lg * ((float)dq * sf));
        float sq = sinf(tq), cq2 = cosf(tq);
        s_q0[l] = (c < 8) ? sq * qd : cq2 * qd;
        s_q1[l] = (c < 8) ? (-cq2 * qd) : sq * qd;
    }
    const VT* vbase = values + ((size_t)b * SS + (size_t)j * 64) * DIMD + c * 64;
#pragma unroll
    for (int i = 0; i < 2; ++i) {
        int f = tid + i * 256;
        int row = f >> 3;
        int c8 = f & 7;
        if constexpr (sizeof(VT) == 2) {
            bhx8 v8 = *reinterpret_cast<const bhx8*>(vbase + (size_t)row * DIMD + c8 * 8);
#pragma unroll
            for (int r = 0; r < 8; ++r) vsm[row][c8 * 8 + r] = (float)v8[r];
        } else {
            *reinterpret_cast<float4*>(&vsm[row][c8 * 8]) =
                *reinterpret_cast<const float4*>(vbase + (size_t)row * DIMD + c8 * 8);
            *reinterpret_cast<float4*>(&vsm[row][c8 * 8 + 4]) =
                *reinterpret_cast<const float4*>(vbase + (size_t)row * DIMD + c8 * 8 + 4);
        }
    }
    if (tid < 128) {
        s_st[tid] = Sws[((size_t)(b * CC + c) * NCH + j) * 128 + tid];
    }
    __syncthreads();
    int l = tid >> 2, eg = tid & 3;
    float acc[16];
#pragma unroll
    for (int i = 0; i < 16; i++) acc[i] = 0.f;
    float q0 = s_q0[l], q1 = s_q1[l], pl_ = s_p[l];
    for (int m = 0; m <= l; ++m) {
        float wgt = (q0 * s_k0[m] + q1 * s_k1[m]) * (pl_ * s_ip[m]);
        const float* vr = &vsm[m][eg * 16];
#pragma unroll
        for (int i = 0; i < 16; i++) acc[i] += wgt * vr[i];
    }
    float al = alphap[c], be = betap[c];
    float* ob = outp + ((size_t)b * SS + (size_t)j * 64 + l) * DIMD + c * 64 + eg * 16;
    const float* st0 = &s_st[eg * 16];
    const float* st1 = &s_st[64 + eg * 16];
#pragma unroll
    for (int i2 = 0; i2 < 4; i2++) {
        float4 vv = *reinterpret_cast<const float4*>(&vsm[l][eg * 16 + i2 * 4]);
        float4 o4;
        const float* vvp = (const float*)&vv;
        float* o4p = (float*)&o4;
#pragma unroll
        for (int r = 0; r < 4; r++) {
            int i = i2 * 4 + r;
            float prevt = pl_ * (q0 * st0[i] + q1 * st1[i]);
            o4p[r] = (prevt + acc[i]) * al + vvp[r] * be;
        }
        *reinterpret_cast<float4*>(ob + i2 * 4) = o4;
    }
}

extern "C" void kernel_launch(void* const* d_in, const int* in_sizes, int n_in,
                              void* d_out, int out_size, void* d_ws, size_t ws_size,
                              hipStream_t stream) {
    const float* inputs = (const float*)d_in[0];
    const float* Wv     = (const float*)d_in[1];
    const float* gammap = (const float*)d_in[2];
    const float* alphap = (const float*)d_in[3];
    const float* betap  = (const float*)d_in[4];
    const int*   ts     = (const int*)d_in[5];
    const int*   nts    = (const int*)d_in[6];
    float* outp = (float*)d_out;
    char* ws = (char*)d_ws;

    float* Aws     = (float*)ws;                    // 4 MiB
    float* plastWs = (float*)(ws + 4194304);        // 32 KiB
    float* Sws     = (float*)(ws + 4227072);        // 4 MiB
    const size_t base   = 8421376;
    const size_t abytes = 67108864;                 // Abf 64 MiB
    const size_t wbytes = 2097152;                  // Wbf 2 MiB
    const size_t vbytes = 67108864;                 // Vbf 64 MiB

    if (ws_size >= base + abytes + wbytes + vbytes) {
        // tier 1: bf16 A/W + bf16 values; ka fused into gemm epilogue
        bh* Abf = (bh*)(ws + base);
        bh* Wbf = (bh*)(ws + base + abytes);
        bh* Vbf = (bh*)(ws + base + abytes + wbytes);
        cvt2_k<<<16896, 256, 0, stream>>>(inputs, Wv, Abf, Wbf);
        gemm256a<bh><<<512, 512, 0, stream>>>(Abf, Wbf, Vbf, ts, gammap, Aws, plastWs);
        kb_k<<<64, 128, 0, stream>>>(Aws, plastWs, Sws);
        kc2_k<<<1024, 256, 0, stream>>>(ts, nts, gammap, alphap, betap, Vbf, Sws, outp);
    } else if (ws_size >= base + abytes + wbytes) {
        // tier 2: bf16 A/W in workspace, f32 values staged in d_out; ka fused
        bh* Abf = (bh*)(ws + base);
        bh* Wbf = (bh*)(ws + base + abytes);
        cvt2_k<<<16896, 256, 0, stream>>>(inputs, Wv, Abf, Wbf);
        gemm256a<float><<<512, 512, 0, stream>>>(Abf, Wbf, outp, ts, gammap, Aws, plastWs);
        kb_k<<<64, 128, 0, stream>>>(Aws, plastWs, Sws);
        kc_k<float><<<8192, 256, 0, stream>>>(ts, nts, gammap, alphap, betap, outp, Sws, outp);
    } else {
        // tier 3: legacy path
        gemm_k<<<2048, 256, 0, stream>>>(inputs, Wv, outp);
        ka_k<float><<<4096, 64, 0, stream>>>(ts, gammap, outp, Aws, plastWs);
        kb_k<<<64, 128, 0, stream>>>(Aws, plastWs, Sws);
        kc_k<float><<<8192, 256, 0, stream>>>(ts, nts, gammap, alphap, betap, outp, Sws, outp);
    }
}